// Round 11
// baseline (907.441 us; speedup 1.0000x reference)
//
#include <hip/hip_runtime.h>
#include <stdint.h>

#define MAX_DEG   10
#define DEG_COUNT 30000
#define N_ATOMS   330000      // 11 * 30000
#define NF        128
#define BATCH     128
#define SSUM_CHUNKS 24        // per degree bucket: 24 x 1250 rows
#define SSUM_CHUNK  1250
#define SMAX_BLOCKS 256
#define SMAX_CHUNK  1290      // ceil(330000/256)

typedef __attribute__((ext_vector_type(8))) short bf16x8;   // 8 bf16 (4 VGPRs)
typedef __attribute__((ext_vector_type(4))) float f32x4;

__device__ __forceinline__ float bf2f(unsigned short h) {
  union { unsigned u; float f; } v; v.u = ((unsigned)h) << 16; return v.f;
}
__device__ __forceinline__ unsigned short f2bf(float f) {
  union { float f; unsigned u; } v; v.f = f;
  unsigned u = v.u;
  unsigned r = (u + 0x7fffu + ((u >> 16) & 1u)) >> 16;   // RNE
  return (unsigned short)r;
}
// monotone float<->uint key: umax(keys) == fmax(floats); key 0 < key(-inf)
__device__ __forceinline__ unsigned fkey(float f) {
  unsigned u = __float_as_uint(f);
  return u ^ ((u & 0x80000000u) ? 0xFFFFFFFFu : 0x80000000u);
}
__device__ __forceinline__ float funkey(unsigned k) {
  unsigned u = (k & 0x80000000u) ? (k ^ 0x80000000u) : ~k;
  return __uint_as_float(u);
}

struct AdjPtrs { const int* p[10]; };

#define NEG_INF_BITS 0xFF800000

// ---------------------------------------------------------------------------
// K0: fused cast + molecule-sum. Grid (SSUM_CHUNKS, 11): block covers 1250
// contiguous rows of ONE degree bucket (d uniform). Linear coalesced reads;
// casts fp32->bf16 (exactly as before), and accumulates per-(molecule,col)
// fp32 sums + counts into a 64KB LDS table via native ds_add_f32 (bank-free:
// word addr = m*128 + lane -> bank = lane&31, 2 lanes/bank). Partial tables
// stored per block; replaces the perm/sort machinery AND the atoms re-read.
// ---------------------------------------------------------------------------
__global__ __launch_bounds__(512) void k_cast_ssum(
    const float2* __restrict__ atomsV,      // fp32 atoms as float2
    const int* __restrict__ membership,
    unsigned* __restrict__ dstU,            // bf16 atoms copy (packed u32)
    float* __restrict__ Spart,              // [264][128][128]
    int* __restrict__ cntPart)              // [264][128]
{
  __shared__ float S[BATCH * 128];
  __shared__ int C[BATCH];
  const int tid = threadIdx.x;
  const int wave = tid >> 6, lane = tid & 63;
  const int c = blockIdx.x, d = blockIdx.y;
  for (int e = tid; e < BATCH * 128; e += 512) S[e] = 0.f;
  if (tid < BATCH) C[tid] = 0;
  __syncthreads();

  const int lo = d * DEG_COUNT + c * SSUM_CHUNK;
  const int hi = lo + SSUM_CHUNK;

  auto doRow = [&](int r) {
    if (r < hi) {
      float2 x = atomsV[(size_t)r * 64 + lane];
      int m = membership[r];
      dstU[(size_t)r * 64 + lane] = (unsigned)f2bf(x.x) | ((unsigned)f2bf(x.y) << 16);
      atomicAdd(&S[m * 128 + lane], x.x);          // col 2*lane
      atomicAdd(&S[m * 128 + 64 + lane], x.y);     // col 2*lane+1
      if (lane == 0) atomicAdd(&C[m], 1);
    }
  };
  for (int r = lo + wave * 4; r < hi; r += 32) {
    doRow(r); doRow(r + 1); doRow(r + 2); doRow(r + 3);
  }
  __syncthreads();

  float* slice = Spart + (size_t)(d * SSUM_CHUNKS + c) * (BATCH * 128);
  for (int e = tid; e < BATCH * 128; e += 512) {
    int p = e & 127;
    int col = (p < 64) ? (2 * p) : (2 * (p - 64) + 1);   // de-permute
    slice[(e & ~127) + col] = S[e];
  }
  if (tid < BATCH) cntPart[(d * SSUM_CHUNKS + c) * BATCH + tid] = C[tid];
}

// ---------------------------------------------------------------------------
// K1a: build BcatT[d][n][k] (bf16), n in [0,128) (activated half only).
// k<128 -> Wrel (deg>=1) | 0, k>=128 -> Wself (2d-1, or 20 for d=0).
// ---------------------------------------------------------------------------
__global__ __launch_bounds__(256) void k_build_b(const float* __restrict__ W,
                                                 unsigned short* __restrict__ BcatT) {
  int idx = blockIdx.x * 256 + threadIdx.x;
  if (idx >= 11 * 128 * 256) return;
  int d = idx >> 15;
  int rem = idx & 32767;
  int n = rem >> 8;          // 0..127
  int k = rem & 255;
  float v;
  if (k < 128) {
    v = (d >= 1) ? W[(2 * (d - 1)) * 16384 + k * 128 + n] : 0.f;
  } else {
    int ks = k - 128;
    int wi = (d >= 1) ? (2 * d - 1) : 20;
    v = W[wi * 16384 + ks * 128 + n];
  }
  BcatT[idx] = f2bf(v);   // idx == d*32768 + n*256 + k
}

// K1b: biascat[d][n] f32 (activated only): b_rel + b_self
__global__ __launch_bounds__(256) void k_build_bias(const float* __restrict__ b,
                                                    float* __restrict__ biascat) {
  int idx = blockIdx.x * 256 + threadIdx.x;
  if (idx >= 11 * 128) return;
  int d = idx >> 7, n = idx & 127;
  float f = (d >= 1) ? (b[(2 * (d - 1)) * 128 + n] + b[(2 * d - 1) * 128 + n])
                     : b[20 * 128 + n];
  biascat[idx] = f;
}

// ---------------------------------------------------------------------------
// Phase-0 helper (fused nsum): one wave computes 16 nsum rows of its block
// into LDS, 2 rows/iter. Bit-identical accumulation to the old k_nsum.
// ---------------------------------------------------------------------------
template<int D>
__device__ __forceinline__ void nsum_phase0(const unsigned* __restrict__ atomsU,
                                            const int* __restrict__ abase,
                                            unsigned* __restrict__ NS,
                                            int rowTile, int wave, int lane) {
  for (int it = 0; it < 8; ++it) {
    int iloc = wave * 16 + it * 2;               // local row 0..127
    int r0 = rowTile * 128 + iloc;
    int sw0 = lane ^ ((iloc & 7) << 2);
    int sw1 = lane ^ (((iloc + 1) & 7) << 2);
    if (r0 < DEG_COUNT - 1) {                    // normal pair (r0, r0+1)
      const int* a = abase + (size_t)r0 * D;
      int myIdx = (lane < 2 * D) ? a[lane] : 0;
      unsigned xs[2 * D];
#pragma unroll
      for (int j = 0; j < 2 * D; ++j) {
        int nbr = __shfl(myIdx, j, 64);
        xs[j] = atomsU[(size_t)nbr * 64 + lane];
      }
      float s0a = 0.f, s1a = 0.f, s0b = 0.f, s1b = 0.f;
#pragma unroll
      for (int j = 0; j < D; ++j) {
        s0a += bf2f((unsigned short)(xs[j] & 0xffff));
        s1a += bf2f((unsigned short)(xs[j] >> 16));
      }
#pragma unroll
      for (int j = D; j < 2 * D; ++j) {
        s0b += bf2f((unsigned short)(xs[j] & 0xffff));
        s1b += bf2f((unsigned short)(xs[j] >> 16));
      }
      NS[(size_t)iloc * 64 + sw0]       = (unsigned)f2bf(s0a) | ((unsigned)f2bf(s1a) << 16);
      NS[(size_t)(iloc + 1) * 64 + sw1] = (unsigned)f2bf(s0b) | ((unsigned)f2bf(s1b) << 16);
    } else {                                     // tail: both rows clamp to 29999
      const int* a = abase + (size_t)(DEG_COUNT - 1) * D;
      int myIdx = (lane < D) ? a[lane] : 0;
      unsigned xs[D];
#pragma unroll
      for (int j = 0; j < D; ++j) {
        int nbr = __shfl(myIdx, j, 64);
        xs[j] = atomsU[(size_t)nbr * 64 + lane];
      }
      float s0 = 0.f, s1 = 0.f;
#pragma unroll
      for (int j = 0; j < D; ++j) {
        s0 += bf2f((unsigned short)(xs[j] & 0xffff));
        s1 += bf2f((unsigned short)(xs[j] >> 16));
      }
      unsigned p = (unsigned)f2bf(s0) | ((unsigned)f2bf(s1) << 16);
      NS[(size_t)iloc * 64 + sw0] = p;
      NS[(size_t)(iloc + 1) * 64 + sw1] = p;
    }
  }
}

// ---------------------------------------------------------------------------
// K3: fused nsum + streaming MFMA GEMM — activated half (128 cols).
// 1D grid, d = bid % 11 (round-robin: heavy d=10 blocks interleaved instead
// of forming the dispatch tail). Plain stores (nt-store theory falsified in
// round 10: FETCH unchanged 246->243MB).
// ---------------------------------------------------------------------------
__global__ __launch_bounds__(512, 4) void k_gemm(
    const unsigned short* __restrict__ atomsBf,
    AdjPtrs adj,
    const unsigned short* __restrict__ BcatT,    // [11][128][256] n-major
    const float* __restrict__ biascat,           // [11][128]
    const float* __restrict__ gamma,
    const float* __restrict__ beta,
    float* __restrict__ out0)                    // xn FINAL (fp32)
{
  const int bid = blockIdx.x;
  const int d = bid % 11;
  const int rowTile = bid / 11;
  const int tid = threadIdx.x;
  const int lane = tid & 63;
  const int wave = tid >> 6;          // 0..7
  const int m16 = lane & 15;
  const int g = lane >> 4;            // k-group 0..3

  __shared__ unsigned short Bs[128 * 256];   // 64 KiB; phase0 NS uses first 32KB
  unsigned* NS = (unsigned*)Bs;              // [128 rows][64 words], swizzled

  const unsigned short* Bd = BcatT + d * 32768;
  const unsigned* atomsU = (const unsigned*)atomsBf;

  // ---- self A-frags (ks 4-7) from global first (overlap with phase 0) ----
  const int rowBase = rowTile * 128 + wave * 16;
  bf16x8 af[8];
  {
    int rbL = rowBase + m16; if (rbL > DEG_COUNT - 1) rbL = DEG_COUNT - 1;
    size_t gr = (size_t)d * DEG_COUNT + rbL;
#pragma unroll
    for (int ks = 4; ks < 8; ++ks)
      af[ks] = *(const bf16x8*)(atomsBf + gr * 128 + (ks - 4) * 32 + g * 8);
  }

  // ---- phase 0: fused nsum into LDS; af ks0-3 from LDS ----
  if (d > 0) {
    const int* abase = adj.p[d - 1];
    switch (d) {
      case 1:  nsum_phase0<1>(atomsU, abase, NS, rowTile, wave, lane); break;
      case 2:  nsum_phase0<2>(atomsU, abase, NS, rowTile, wave, lane); break;
      case 3:  nsum_phase0<3>(atomsU, abase, NS, rowTile, wave, lane); break;
      case 4:  nsum_phase0<4>(atomsU, abase, NS, rowTile, wave, lane); break;
      case 5:  nsum_phase0<5>(atomsU, abase, NS, rowTile, wave, lane); break;
      case 6:  nsum_phase0<6>(atomsU, abase, NS, rowTile, wave, lane); break;
      case 7:  nsum_phase0<7>(atomsU, abase, NS, rowTile, wave, lane); break;
      case 8:  nsum_phase0<8>(atomsU, abase, NS, rowTile, wave, lane); break;
      case 9:  nsum_phase0<9>(atomsU, abase, NS, rowTile, wave, lane); break;
      default: nsum_phase0<10>(atomsU, abase, NS, rowTile, wave, lane); break;
    }
    __syncthreads();
    const char* nsb = (const char*)NS;
    const int rowb = (wave * 16 + m16) * 256;         // byte base, local row
    const int sw = (m16 & 7) << 4;
#pragma unroll
    for (int ks = 0; ks < 4; ++ks)
      af[ks] = *(const bf16x8*)(nsb + ((rowb + ks * 64 + g * 16) ^ sw));
    __syncthreads();   // protect NS before B-panel overwrite
  } else {
    bf16x8 z = {0, 0, 0, 0, 0, 0, 0, 0};
#pragma unroll
    for (int ks = 0; ks < 4; ++ks) af[ks] = z;
  }

  // ---- stage B: 512 threads x 8 x 16B = 64KB, swizzled dest ----
#pragma unroll
  for (int it = 0; it < 8; ++it) {
    int flat = it * 512 + tid;        // chunk of 16B; 32 chunks per row
    int row = flat >> 5;              // 0..127
    int c = flat & 31;
    uint4 v = *(const uint4*)(Bd + row * 256 + c * 8);
    int kb = (c * 16) ^ ((row & 7) << 4);
    *(uint4*)((char*)Bs + row * 512 + kb) = v;
  }

  __syncthreads();

  const int ldsMask = (m16 & 7) << 4;

  f32x4 acc[8];
#pragma unroll
  for (int ct = 0; ct < 8; ++ct) acc[ct] = (f32x4){0.f, 0.f, 0.f, 0.f};

#pragma unroll
  for (int ct = 0; ct < 8; ++ct) {
    const char* bbase = (const char*)Bs + (ct * 16 + m16) * 512;
    bf16x8 bf[8];
#pragma unroll
    for (int ks = 0; ks < 8; ++ks)
      bf[ks] = *(const bf16x8*)(bbase + ((ks * 64 + g * 16) ^ ldsMask));
#pragma unroll
    for (int ks = 0; ks < 8; ++ks)
      acc[ct] = __builtin_amdgcn_mfma_f32_16x16x32_bf16(af[ks], bf[ks], acc[ct], 0, 0, 0);
  }

  // ---- epilogue: bias, LN over 128 cols, coalesced stores ----
  float bias_[8], gam[8], bet[8];
#pragma unroll
  for (int ct = 0; ct < 8; ++ct) {
    bias_[ct] = biascat[d * 128 + ct * 16 + m16];
    gam[ct] = gamma[ct * 16 + m16];
    bet[ct] = beta[ct * 16 + m16];
  }

#pragma unroll
  for (int ct = 0; ct < 8; ++ct)
#pragma unroll
    for (int r = 0; r < 4; ++r) acc[ct][r] += bias_[ct];

  float s[4], qq[4];
#pragma unroll
  for (int r = 0; r < 4; ++r) {
    s[r] = 0.f; qq[r] = 0.f;
#pragma unroll
    for (int ct = 0; ct < 8; ++ct) {
      float v = acc[ct][r];
      s[r] += v; qq[r] += v * v;
    }
  }
#pragma unroll
  for (int off = 8; off >= 1; off >>= 1) {
#pragma unroll
    for (int r = 0; r < 4; ++r) {
      s[r]  += __shfl_xor(s[r],  off, 64);
      qq[r] += __shfl_xor(qq[r], off, 64);
    }
  }

#pragma unroll
  for (int r = 0; r < 4; ++r) {
    int rb = rowBase + g * 4 + r;
    float mean = s[r] * (1.0f / 128.0f);
    float var  = qq[r] * (1.0f / 128.0f) - mean * mean;
    float inv  = 1.0f / (sqrtf(var + 1e-5f) + 1e-5f);   // ref: sqrt(var+eps)+eps
    if (rb < DEG_COUNT) {
      size_t grow = (size_t)d * DEG_COUNT + rb;
#pragma unroll
      for (int ct = 0; ct < 8; ++ct)
        out0[grow * 128 + ct * 16 + m16] = gam[ct] * ((acc[ct][r] - mean) * inv) + bet[ct];
    }
  }
}

// ---------------------------------------------------------------------------
// K_smax: linear scan of xn -> per-block LDS segment-max table (monotone-key
// ds_max_u32, bank-free) -> 256 partial key tables. No sort, no perm.
// ---------------------------------------------------------------------------
__global__ __launch_bounds__(512) void k_smax(
    const float2* __restrict__ xnV,
    const int* __restrict__ membership,
    unsigned* __restrict__ kmaxPart)        // [256][128][128] keys
{
  __shared__ unsigned K[BATCH * 128];
  const int tid = threadIdx.x;
  const int wave = tid >> 6, lane = tid & 63;
  for (int e = tid; e < BATCH * 128; e += 512) K[e] = 0u;   // 0 < key(-inf)
  __syncthreads();

  const int lo = blockIdx.x * SMAX_CHUNK;
  const int hi = min(lo + SMAX_CHUNK, N_ATOMS);

  auto doRow = [&](int r) {
    if (r < hi) {
      float2 x = xnV[(size_t)r * 64 + lane];
      int m = membership[r];
      atomicMax(&K[m * 128 + lane], fkey(x.x));
      atomicMax(&K[m * 128 + 64 + lane], fkey(x.y));
    }
  };
  for (int r = lo + wave * 4; r < hi; r += 32) {
    doRow(r); doRow(r + 1); doRow(r + 2); doRow(r + 3);
  }
  __syncthreads();

  unsigned* slice = kmaxPart + (size_t)blockIdx.x * (BATCH * 128);
  for (int e = tid; e < BATCH * 128; e += 512) {
    int p = e & 127;
    int col = (p < 64) ? (2 * p) : (2 * (p - 64) + 1);   // de-permute
    slice[(e & ~127) + col] = K[e];
  }
}

// ---------------------------------------------------------------------------
// K_ynfinal: merge 264 S-slices + counts -> yn GEMM + LN -> out1;
// merge 256 max-key slices -> out2. 128 blocks x 128 threads.
// ---------------------------------------------------------------------------
__global__ __launch_bounds__(128) void k_ynfinal(
    const float* __restrict__ Spart,        // [264][128][128]
    const int* __restrict__ cntPart,        // [264][128]
    const unsigned* __restrict__ kmaxPart,  // [256][128][128]
    const float* __restrict__ W,
    const float* __restrict__ b,
    const float* __restrict__ gamma,
    const float* __restrict__ beta,
    float* __restrict__ out1,
    float* __restrict__ out2)
{
  int m = blockIdx.x;
  int j = threadIdx.x;

  // ---- max merge ----
  unsigned km = 0u;
#pragma unroll 4
  for (int s = 0; s < SMAX_BLOCKS; ++s)
    km = max(km, kmaxPart[(size_t)s * (BATCH * 128) + m * 128 + j]);
  out2[m * 128 + j] = (km == 0u) ? __int_as_float((int)NEG_INF_BITS) : funkey(km);

  // ---- S / cnt merge ----
  __shared__ float Sm[11][128];
  __shared__ float cw[11];
  for (int e = j; e < 11 * 128; e += 128) {
    int d = e >> 7, cix = e & 127;
    float t = 0.f;
#pragma unroll 4
    for (int c = 0; c < SSUM_CHUNKS; ++c)
      t += Spart[(size_t)(d * SSUM_CHUNKS + c) * (BATCH * 128) + m * 128 + cix];
    Sm[d][cix] = t;
  }
  if (j < 11) {
    int t = 0;
#pragma unroll
    for (int c = 0; c < SSUM_CHUNKS; ++c)
      t += cntPart[(j * SSUM_CHUNKS + c) * BATCH + m];
    cw[j] = (float)t;
  }
  __syncthreads();

  // ---- yn = LN( sum_d Sm[d] @ Wg_d + cw[d]*bg_d ) ----
  float acc = 0.f;
  for (int d = 0; d < 11; ++d) {
    int wi = (d >= 1) ? (20 + d) : 31;
    const float* Wd = W + wi * 16384;
    float a0 = 0.f, a1 = 0.f, a2 = 0.f, a3 = 0.f;
    for (int k = 0; k < 128; k += 4) {
      a0 += Sm[d][k]     * Wd[k * 128 + j];
      a1 += Sm[d][k + 1] * Wd[(k + 1) * 128 + j];
      a2 += Sm[d][k + 2] * Wd[(k + 2) * 128 + j];
      a3 += Sm[d][k + 3] * Wd[(k + 3) * 128 + j];
    }
    acc += (a0 + a1) + (a2 + a3);
    acc += cw[d] * b[wi * 128 + j];
  }

  float ws_ = acc, wq = acc * acc;
#pragma unroll
  for (int off = 32; off >= 1; off >>= 1) {
    ws_ += __shfl_xor(ws_, off, 64);
    wq  += __shfl_xor(wq, off, 64);
  }
  __shared__ float red[4];
  int wave = j >> 6, lane = j & 63;
  if (lane == 0) { red[wave * 2] = ws_; red[wave * 2 + 1] = wq; }
  __syncthreads();
  float Ssum = red[0] + red[2], Q = red[1] + red[3];
  float mean = Ssum * (1.f / 128.f);
  float var = Q * (1.f / 128.f) - mean * mean;
  float inv = 1.f / (sqrtf(var + 1e-5f) + 1e-5f);
  out1[m * 128 + j] = gamma[j] * ((acc - mean) * inv) + beta[j];
}

// ---------------------------------------------------------------------------
extern "C" void kernel_launch(void* const* d_in, const int* in_sizes, int n_in,
                              void* d_out, int out_size, void* d_ws, size_t ws_size,
                              hipStream_t stream) {
  const float* atoms = (const float*)d_in[0];
  // d_in[1] = deg_slice (unused; buckets are static)
  const int* membership = (const int*)d_in[2];
  AdjPtrs adj;
  for (int i = 0; i < 10; ++i) adj.p[i] = (const int*)d_in[3 + i];
  const float* W     = (const float*)d_in[13];
  const float* b     = (const float*)d_in[14];
  const float* gamma = (const float*)d_in[15];
  const float* beta  = (const float*)d_in[16];

  char* ws = (char*)d_ws;
  size_t off = 0;
  unsigned short* atomsBf = (unsigned short*)(ws + off); off += (size_t)N_ATOMS * 128 * 2;
  unsigned short* BcatT   = (unsigned short*)(ws + off); off += (size_t)11 * 128 * 256 * 2;
  float* biascat          = (float*)(ws + off);          off += (size_t)11 * 128 * 4;
  float* Spart            = (float*)(ws + off);          off += (size_t)11 * SSUM_CHUNKS * BATCH * 128 * 4;
  int* cntPart            = (int*)(ws + off);            off += (size_t)11 * SSUM_CHUNKS * BATCH * 4;
  unsigned* kmaxPart      = (unsigned*)(ws + off);       off += (size_t)SMAX_BLOCKS * BATCH * 128 * 4;

  float* out0 = (float*)d_out;
  float* out1 = out0 + (size_t)N_ATOMS * 128;
  float* out2 = out1 + 16384;

  hipLaunchKernelGGL(k_build_b, dim3((11 * 128 * 256 + 255) / 256), dim3(256), 0, stream, W, BcatT);
  hipLaunchKernelGGL(k_build_bias, dim3((11 * 128 + 255) / 256), dim3(256), 0, stream, b, biascat);
  // fused cast + per-(molecule,degree) sums (replaces cast + sort + msum)
  hipLaunchKernelGGL(k_cast_ssum, dim3(SSUM_CHUNKS, 11), dim3(512), 0, stream,
                     (const float2*)atoms, membership, (unsigned*)atomsBf, Spart, cntPart);
  // fused nsum + activated GEMM + LN (round-robin degree mapping)
  hipLaunchKernelGGL(k_gemm, dim3(236 * 11), dim3(512), 0, stream,
                     atomsBf, adj, BcatT, biascat, gamma, beta, out0);
  // linear segment-max of xn (LDS monotone-key tables, no sort)
  hipLaunchKernelGGL(k_smax, dim3(SMAX_BLOCKS), dim3(512), 0, stream,
                     (const float2*)out0, membership, kmaxPart);
  // yn (algebraic gathered path) + max merge
  hipLaunchKernelGGL(k_ynfinal, dim3(128), dim3(128), 0, stream,
                     Spart, cntPart, kmaxPart, W, b, gamma, beta, out1, out2);
}

// Round 12
// 596.243 us; speedup vs baseline: 1.5219x; 1.5219x over previous
//
#include <hip/hip_runtime.h>
#include <stdint.h>

#define MAX_DEG   10
#define DEG_COUNT 30000
#define N_ATOMS   330000      // 11 * 30000
#define NF        128
#define BATCH     128
#define SORT_BLOCKS 256
#define SORT_CHUNK  1290      // ceil(330000/256)

typedef __attribute__((ext_vector_type(8))) short bf16x8;   // 8 bf16 (4 VGPRs)
typedef __attribute__((ext_vector_type(4))) float f32x4;
typedef __attribute__((ext_vector_type(2))) float f32x2;

__device__ __forceinline__ float bf2f(unsigned short h) {
  union { unsigned u; float f; } v; v.u = ((unsigned)h) << 16; return v.f;
}
__device__ __forceinline__ unsigned short f2bf(float f) {
  union { float f; unsigned u; } v; v.f = f;
  unsigned u = v.u;
  unsigned r = (u + 0x7fffu + ((u >> 16) & 1u)) >> 16;   // RNE
  return (unsigned short)r;
}

struct AdjPtrs { const int* p[10]; };

#define NEG_INF_BITS 0xFF800000

// ---------------------------------------------------------------------------
// K0: fused cast + per-block membership histogram. Both stream the same rows
// linearly. Histogram uses INT LDS atomics (native ds ops — the f32 LDS
// atomicAdd path is a CAS loop without -munsafe-fp-atomics; rounds 3/11's
// 220-420us "idle" kernels were exactly that).
// Cast packing bit-identical to the old k_cast.
// ---------------------------------------------------------------------------
__global__ __launch_bounds__(512) void k_cast_hist(
    const float2* __restrict__ atomsV,      // fp32 atoms as float2
    const int* __restrict__ membership,
    unsigned* __restrict__ dstU,            // bf16 atoms copy (packed u32)
    int* __restrict__ blockHist)            // [SORT_BLOCKS][128]
{
  __shared__ int bins[BATCH];
  const int tid = threadIdx.x;
  const int wave = tid >> 6, lane = tid & 63;
  if (tid < BATCH) bins[tid] = 0;
  __syncthreads();

  const int lo = blockIdx.x * SORT_CHUNK;
  const int hi = min(lo + SORT_CHUNK, N_ATOMS);

  // histogram: native int LDS atomics, 512-thread stride
  for (int i = lo + tid; i < hi; i += 512)
    atomicAdd(&bins[membership[i]], 1);

  // cast: per-lane float2 -> packed bf16 u32, 4-row unroll for MLP
  auto doRow = [&](int r) {
    if (r < hi) {
      float2 x = atomsV[(size_t)r * 64 + lane];
      dstU[(size_t)r * 64 + lane] = (unsigned)f2bf(x.x) | ((unsigned)f2bf(x.y) << 16);
    }
  };
  for (int r = lo + wave * 4; r < hi; r += 32) {
    doRow(r); doRow(r + 1); doRow(r + 2); doRow(r + 3);
  }

  __syncthreads();
  if (tid < BATCH) blockHist[blockIdx.x * BATCH + tid] = bins[tid];
}

// ---------------------------------------------------------------------------
// K1: build BcatT[d][n][k] (bf16, activated half) + biascat in one launch.
// ---------------------------------------------------------------------------
__global__ __launch_bounds__(256) void k_build_bb(const float* __restrict__ W,
                                                  const float* __restrict__ b,
                                                  unsigned short* __restrict__ BcatT,
                                                  float* __restrict__ biascat) {
  int idx = blockIdx.x * 256 + threadIdx.x;
  if (idx < 11 * 128) {           // bias: [d][n]
    int d = idx >> 7, n = idx & 127;
    float f = (d >= 1) ? (b[(2 * (d - 1)) * 128 + n] + b[(2 * d - 1) * 128 + n])
                       : b[20 * 128 + n];
    biascat[idx] = f;
  }
  if (idx >= 11 * 128 * 256) return;
  int d = idx >> 15;
  int rem = idx & 32767;
  int n = rem >> 8;          // 0..127
  int k = rem & 255;
  float v;
  if (k < 128) {
    v = (d >= 1) ? W[(2 * (d - 1)) * 16384 + k * 128 + n] : 0.f;
  } else {
    int ks = k - 128;
    int wi = (d >= 1) ? (2 * d - 1) : 20;
    v = W[wi * 16384 + ks * 128 + n];
  }
  BcatT[idx] = f2bf(v);   // idx == d*32768 + n*256 + k
}

// ---------------------------------------------------------------------------
// Phase-0 helper (fused nsum): one wave computes 16 nsum rows of its block
// into LDS, 2 rows/iter. Bit-identical accumulation to the old k_nsum.
// ---------------------------------------------------------------------------
template<int D>
__device__ __forceinline__ void nsum_phase0(const unsigned* __restrict__ atomsU,
                                            const int* __restrict__ abase,
                                            unsigned* __restrict__ NS,
                                            int rowTile, int wave, int lane) {
  for (int it = 0; it < 8; ++it) {
    int iloc = wave * 16 + it * 2;               // local row 0..127
    int r0 = rowTile * 128 + iloc;
    int sw0 = lane ^ ((iloc & 7) << 2);
    int sw1 = lane ^ (((iloc + 1) & 7) << 2);
    if (r0 < DEG_COUNT - 1) {                    // normal pair (r0, r0+1)
      const int* a = abase + (size_t)r0 * D;
      int myIdx = (lane < 2 * D) ? a[lane] : 0;
      unsigned xs[2 * D];
#pragma unroll
      for (int j = 0; j < 2 * D; ++j) {
        int nbr = __shfl(myIdx, j, 64);
        xs[j] = atomsU[(size_t)nbr * 64 + lane];
      }
      float s0a = 0.f, s1a = 0.f, s0b = 0.f, s1b = 0.f;
#pragma unroll
      for (int j = 0; j < D; ++j) {
        s0a += bf2f((unsigned short)(xs[j] & 0xffff));
        s1a += bf2f((unsigned short)(xs[j] >> 16));
      }
#pragma unroll
      for (int j = D; j < 2 * D; ++j) {
        s0b += bf2f((unsigned short)(xs[j] & 0xffff));
        s1b += bf2f((unsigned short)(xs[j] >> 16));
      }
      NS[(size_t)iloc * 64 + sw0]       = (unsigned)f2bf(s0a) | ((unsigned)f2bf(s1a) << 16);
      NS[(size_t)(iloc + 1) * 64 + sw1] = (unsigned)f2bf(s0b) | ((unsigned)f2bf(s1b) << 16);
    } else {                                     // tail: both rows clamp to 29999
      const int* a = abase + (size_t)(DEG_COUNT - 1) * D;
      int myIdx = (lane < D) ? a[lane] : 0;
      unsigned xs[D];
#pragma unroll
      for (int j = 0; j < D; ++j) {
        int nbr = __shfl(myIdx, j, 64);
        xs[j] = atomsU[(size_t)nbr * 64 + lane];
      }
      float s0 = 0.f, s1 = 0.f;
#pragma unroll
      for (int j = 0; j < D; ++j) {
        s0 += bf2f((unsigned short)(xs[j] & 0xffff));
        s1 += bf2f((unsigned short)(xs[j] >> 16));
      }
      unsigned p = (unsigned)f2bf(s0) | ((unsigned)f2bf(s1) << 16);
      NS[(size_t)iloc * 64 + sw0] = p;
      NS[(size_t)(iloc + 1) * 64 + sw1] = p;
    }
  }
}

// ---------------------------------------------------------------------------
// K3: fused nsum + streaming MFMA GEMM — activated half (128 cols).
// Round-10 structure (2 blocks/CU), plain stores (nt falsified).
// ---------------------------------------------------------------------------
__global__ __launch_bounds__(512, 4) void k_gemm(
    const unsigned short* __restrict__ atomsBf,
    AdjPtrs adj,
    const unsigned short* __restrict__ BcatT,    // [11][128][256] n-major
    const float* __restrict__ biascat,           // [11][128]
    const float* __restrict__ gamma,
    const float* __restrict__ beta,
    float* __restrict__ out0)                    // xn FINAL (fp32)
{
  const int d = blockIdx.y;
  const int rowTile = blockIdx.x;
  const int tid = threadIdx.x;
  const int lane = tid & 63;
  const int wave = tid >> 6;          // 0..7
  const int m16 = lane & 15;
  const int g = lane >> 4;            // k-group 0..3

  __shared__ unsigned short Bs[128 * 256];   // 64 KiB; phase0 NS uses first 32KB
  unsigned* NS = (unsigned*)Bs;              // [128 rows][64 words], swizzled

  const unsigned short* Bd = BcatT + d * 32768;
  const unsigned* atomsU = (const unsigned*)atomsBf;

  // ---- self A-frags (ks 4-7) from global first (overlap with phase 0) ----
  const int rowBase = rowTile * 128 + wave * 16;
  bf16x8 af[8];
  {
    int rbL = rowBase + m16; if (rbL > DEG_COUNT - 1) rbL = DEG_COUNT - 1;
    size_t gr = (size_t)d * DEG_COUNT + rbL;
#pragma unroll
    for (int ks = 4; ks < 8; ++ks)
      af[ks] = *(const bf16x8*)(atomsBf + gr * 128 + (ks - 4) * 32 + g * 8);
  }

  // ---- phase 0: fused nsum into LDS; af ks0-3 from LDS ----
  if (d > 0) {
    const int* abase = adj.p[d - 1];
    switch (d) {
      case 1:  nsum_phase0<1>(atomsU, abase, NS, rowTile, wave, lane); break;
      case 2:  nsum_phase0<2>(atomsU, abase, NS, rowTile, wave, lane); break;
      case 3:  nsum_phase0<3>(atomsU, abase, NS, rowTile, wave, lane); break;
      case 4:  nsum_phase0<4>(atomsU, abase, NS, rowTile, wave, lane); break;
      case 5:  nsum_phase0<5>(atomsU, abase, NS, rowTile, wave, lane); break;
      case 6:  nsum_phase0<6>(atomsU, abase, NS, rowTile, wave, lane); break;
      case 7:  nsum_phase0<7>(atomsU, abase, NS, rowTile, wave, lane); break;
      case 8:  nsum_phase0<8>(atomsU, abase, NS, rowTile, wave, lane); break;
      case 9:  nsum_phase0<9>(atomsU, abase, NS, rowTile, wave, lane); break;
      default: nsum_phase0<10>(atomsU, abase, NS, rowTile, wave, lane); break;
    }
    __syncthreads();
    const char* nsb = (const char*)NS;
    const int rowb = (wave * 16 + m16) * 256;         // byte base, local row
    const int sw = (m16 & 7) << 4;
#pragma unroll
    for (int ks = 0; ks < 4; ++ks)
      af[ks] = *(const bf16x8*)(nsb + ((rowb + ks * 64 + g * 16) ^ sw));
    __syncthreads();   // protect NS before B-panel overwrite
  } else {
    bf16x8 z = {0, 0, 0, 0, 0, 0, 0, 0};
#pragma unroll
    for (int ks = 0; ks < 4; ++ks) af[ks] = z;
  }

  // ---- stage B: 512 threads x 8 x 16B = 64KB, swizzled dest ----
#pragma unroll
  for (int it = 0; it < 8; ++it) {
    int flat = it * 512 + tid;        // chunk of 16B; 32 chunks per row
    int row = flat >> 5;              // 0..127
    int c = flat & 31;
    uint4 v = *(const uint4*)(Bd + row * 256 + c * 8);
    int kb = (c * 16) ^ ((row & 7) << 4);
    *(uint4*)((char*)Bs + row * 512 + kb) = v;
  }

  __syncthreads();

  const int ldsMask = (m16 & 7) << 4;

  f32x4 acc[8];
#pragma unroll
  for (int ct = 0; ct < 8; ++ct) acc[ct] = (f32x4){0.f, 0.f, 0.f, 0.f};

#pragma unroll
  for (int ct = 0; ct < 8; ++ct) {
    const char* bbase = (const char*)Bs + (ct * 16 + m16) * 512;
    bf16x8 bf[8];
#pragma unroll
    for (int ks = 0; ks < 8; ++ks)
      bf[ks] = *(const bf16x8*)(bbase + ((ks * 64 + g * 16) ^ ldsMask));
#pragma unroll
    for (int ks = 0; ks < 8; ++ks)
      acc[ct] = __builtin_amdgcn_mfma_f32_16x16x32_bf16(af[ks], bf[ks], acc[ct], 0, 0, 0);
  }

  // ---- epilogue: bias, LN over 128 cols, coalesced stores ----
  float bias_[8], gam[8], bet[8];
#pragma unroll
  for (int ct = 0; ct < 8; ++ct) {
    bias_[ct] = biascat[d * 128 + ct * 16 + m16];
    gam[ct] = gamma[ct * 16 + m16];
    bet[ct] = beta[ct * 16 + m16];
  }

#pragma unroll
  for (int ct = 0; ct < 8; ++ct)
#pragma unroll
    for (int r = 0; r < 4; ++r) acc[ct][r] += bias_[ct];

  float s[4], qq[4];
#pragma unroll
  for (int r = 0; r < 4; ++r) {
    s[r] = 0.f; qq[r] = 0.f;
#pragma unroll
    for (int ct = 0; ct < 8; ++ct) {
      float v = acc[ct][r];
      s[r] += v; qq[r] += v * v;
    }
  }
#pragma unroll
  for (int off = 8; off >= 1; off >>= 1) {
#pragma unroll
    for (int r = 0; r < 4; ++r) {
      s[r]  += __shfl_xor(s[r],  off, 64);
      qq[r] += __shfl_xor(qq[r], off, 64);
    }
  }

#pragma unroll
  for (int r = 0; r < 4; ++r) {
    int rb = rowBase + g * 4 + r;
    float mean = s[r] * (1.0f / 128.0f);
    float var  = qq[r] * (1.0f / 128.0f) - mean * mean;
    float inv  = 1.0f / (sqrtf(var + 1e-5f) + 1e-5f);   // ref: sqrt(var+eps)+eps
    if (rb < DEG_COUNT) {
      size_t grow = (size_t)d * DEG_COUNT + rb;
#pragma unroll
      for (int ct = 0; ct < 8; ++ct)
        out0[grow * 128 + ct * 16 + m16] = gam[ct] * ((acc[ct][r] - mean) * inv) + bet[ct];
    }
  }
}

// ---------------------------------------------------------------------------
// Counting sort tail (scan + scatter); hist fused into k_cast_hist.
// ---------------------------------------------------------------------------
__global__ __launch_bounds__(128) void k_scan2(const int* __restrict__ blockHist,
                                               int* __restrict__ off,     // [SORT_BLOCKS][128]
                                               int* __restrict__ base,
                                               int* __restrict__ hist) {
  int m = threadIdx.x;
  int tot = 0;
  for (int b = 0; b < SORT_BLOCKS; ++b) tot += blockHist[b * BATCH + m];
  hist[m] = tot;
  __shared__ int t[BATCH];
  t[m] = tot;
  __syncthreads();
  int acc = 0;
  for (int i = 0; i < m; ++i) acc += t[i];
  base[m] = acc;
  int run = acc;
  for (int b = 0; b < SORT_BLOCKS; ++b) {
    off[b * BATCH + m] = run;
    run += blockHist[b * BATCH + m];
  }
}

__global__ __launch_bounds__(256) void k_scatter2(const int* __restrict__ membership,
                                                  const int* __restrict__ off,
                                                  int* __restrict__ perm) {
  __shared__ int bins[BATCH];
  int tid = threadIdx.x;
  if (tid < BATCH) bins[tid] = off[blockIdx.x * BATCH + tid];
  __syncthreads();
  int lo = blockIdx.x * SORT_CHUNK, hi = min(lo + SORT_CHUNK, N_ATOMS);
  for (int i = lo + tid; i < hi; i += 256) {
    int m = membership[i];
    int pos = atomicAdd(&bins[m], 1);   // native int LDS atomic
    perm[pos] = i;
  }
}

// ---------------------------------------------------------------------------
// K_mreduce: ONE perm pass doing BOTH segment-max(xn) AND per-(molecule,
// degree) atom sums + counts. Per-wave LDS tables with PLAIN adds (no
// atomics — the sort makes each (wave,slice) range exclusive).
// ---------------------------------------------------------------------------
__global__ __launch_bounds__(512) void k_mreduce(
    const f32x2* __restrict__ xnV,          // out0 as f32x2
    const unsigned* __restrict__ atomsU,
    const int* __restrict__ perm,
    const int* __restrict__ base,
    const int* __restrict__ hist,
    float* __restrict__ Spart,      // [4][128][11][128]
    int* __restrict__ cntPart,      // [4][128][11]
    float2* __restrict__ pmax4)     // [4][128][64] float2
{
  const int m = blockIdx.x >> 2;
  const int s = blockIdx.x & 3;
  const int b0 = base[m], cnt = hist[m];
  const int lo = b0 + (cnt * s) / 4;
  const int hi = b0 + (cnt * (s + 1)) / 4;
  const int wave = threadIdx.x >> 6, lane = threadIdx.x & 63;

  __shared__ float S[8][11][128];   // physical col p: p<64 -> col 2p, else 2(p-64)+1
  __shared__ int C[8][11];
  __shared__ float2 maxT[8][64];
  for (int e = lane; e < 11 * 128; e += 64) S[wave][e >> 7][e & 127] = 0.f;
  if (lane < 11) C[wave][lane] = 0;
  __syncthreads();

  const float NEG_INF = __int_as_float((int)NEG_INF_BITS);
  float mx0 = NEG_INF, mx1 = NEG_INF;

  for (int i = lo + wave; i < hi; i += 8) {
    int r = perm[i];
    int d = r / DEG_COUNT;                      // wave-uniform
    f32x2 x = __builtin_nontemporal_load(xnV + (size_t)r * 64 + lane);
    unsigned a = __builtin_nontemporal_load(atomsU + (size_t)r * 64 + lane);
    mx0 = fmaxf(mx0, x[0]);
    mx1 = fmaxf(mx1, x[1]);
    S[wave][d][lane]      += bf2f((unsigned short)(a & 0xffff));   // plain LDS add
    S[wave][d][64 + lane] += bf2f((unsigned short)(a >> 16));
    if (lane == 0) C[wave][d]++;
  }
  maxT[wave][lane] = make_float2(mx0, mx1);
  __syncthreads();

  if (threadIdx.x < 64) {
    int l = threadIdx.x;
    float2 mm = maxT[0][l];
#pragma unroll
    for (int w = 1; w < 8; ++w) {
      float2 b = maxT[w][l]; mm.x = fmaxf(mm.x, b.x); mm.y = fmaxf(mm.y, b.y);
    }
    pmax4[(s * 128 + m) * 64 + l] = mm;
  }
  for (int e = threadIdx.x; e < 11 * 128; e += 512) {
    int d = e >> 7, p = e & 127;
    float t = 0.f;
#pragma unroll
    for (int w = 0; w < 8; ++w) t += S[w][d][p];
    int col = (p < 64) ? (2 * p) : (2 * (p - 64) + 1);   // de-permute
    Spart[(((size_t)s * 128 + m) * 11 + d) * 128 + col] = t;
  }
  if (threadIdx.x < 11) {
    int t = 0;
#pragma unroll
    for (int w = 0; w < 8; ++w) t += C[w][threadIdx.x];
    cntPart[((size_t)s * 128 + m) * 11 + threadIdx.x] = t;
  }
}

// ---------------------------------------------------------------------------
// K_ynfinal: yn = LN( sum_d S[m,d] @ Wg_d + cnt[m,d]*bg_d ) -> out1, and
// merge 4 max slices -> out2. 128 blocks x 128 threads.
// ---------------------------------------------------------------------------
__global__ __launch_bounds__(128) void k_ynfinal(
    const float* __restrict__ Spart,
    const int* __restrict__ cntPart,
    const float* __restrict__ W,
    const float* __restrict__ b,
    const float* __restrict__ gamma,
    const float* __restrict__ beta,
    const float* __restrict__ pmax4,        // [4][128][128]
    float* __restrict__ out1,
    float* __restrict__ out2)
{
  int m = blockIdx.x;
  int j = threadIdx.x;

  float g = __int_as_float((int)NEG_INF_BITS);
#pragma unroll
  for (int sl = 0; sl < 4; ++sl)
    g = fmaxf(g, pmax4[(sl * 128 + m) * 128 + j]);
  out2[m * 128 + j] = g;

  __shared__ float Sm[11][128];
  __shared__ float cw[11];
  for (int e = j; e < 11 * 128; e += 128) {
    int d = e >> 7, c = e & 127;
    float t = 0.f;
#pragma unroll
    for (int sl = 0; sl < 4; ++sl)
      t += Spart[(((size_t)sl * 128 + m) * 11 + d) * 128 + c];
    Sm[d][c] = t;
  }
  if (j < 11) {
    int t = 0;
#pragma unroll
    for (int sl = 0; sl < 4; ++sl) t += cntPart[((size_t)sl * 128 + m) * 11 + j];
    cw[j] = (float)t;
  }
  __syncthreads();

  float acc = 0.f;
  for (int d = 0; d < 11; ++d) {
    int wi = (d >= 1) ? (20 + d) : 31;
    const float* Wd = W + wi * 16384;
    float a0 = 0.f, a1 = 0.f, a2 = 0.f, a3 = 0.f;
    for (int k = 0; k < 128; k += 4) {
      a0 += Sm[d][k]     * Wd[k * 128 + j];
      a1 += Sm[d][k + 1] * Wd[(k + 1) * 128 + j];
      a2 += Sm[d][k + 2] * Wd[(k + 2) * 128 + j];
      a3 += Sm[d][k + 3] * Wd[(k + 3) * 128 + j];
    }
    acc += (a0 + a1) + (a2 + a3);
    acc += cw[d] * b[wi * 128 + j];
  }

  float ws_ = acc, wq = acc * acc;
#pragma unroll
  for (int off = 32; off >= 1; off >>= 1) {
    ws_ += __shfl_xor(ws_, off, 64);
    wq  += __shfl_xor(wq, off, 64);
  }
  __shared__ float red[4];
  int wave = j >> 6, lane = j & 63;
  if (lane == 0) { red[wave * 2] = ws_; red[wave * 2 + 1] = wq; }
  __syncthreads();
  float Ssum = red[0] + red[2], Q = red[1] + red[3];
  float mean = Ssum * (1.f / 128.f);
  float var = Q * (1.f / 128.f) - mean * mean;
  float inv = 1.f / (sqrtf(var + 1e-5f) + 1e-5f);
  out1[m * 128 + j] = gamma[j] * ((acc - mean) * inv) + beta[j];
}

// ---------------------------------------------------------------------------
extern "C" void kernel_launch(void* const* d_in, const int* in_sizes, int n_in,
                              void* d_out, int out_size, void* d_ws, size_t ws_size,
                              hipStream_t stream) {
  const float* atoms = (const float*)d_in[0];
  // d_in[1] = deg_slice (unused; buckets are static)
  const int* membership = (const int*)d_in[2];
  AdjPtrs adj;
  for (int i = 0; i < 10; ++i) adj.p[i] = (const int*)d_in[3 + i];
  const float* W     = (const float*)d_in[13];
  const float* b     = (const float*)d_in[14];
  const float* gamma = (const float*)d_in[15];
  const float* beta  = (const float*)d_in[16];

  char* ws = (char*)d_ws;
  size_t off = 0;
  unsigned short* atomsBf = (unsigned short*)(ws + off); off += (size_t)N_ATOMS * 128 * 2;
  unsigned short* BcatT   = (unsigned short*)(ws + off); off += (size_t)11 * 128 * 256 * 2;
  float* biascat          = (float*)(ws + off);          off += (size_t)11 * 128 * 4;
  int* perm               = (int*)(ws + off);            off += (size_t)N_ATOMS * 4;
  int* hist               = (int*)(ws + off);            off += 512;
  int* base_              = (int*)(ws + off);            off += 512;
  int* blockHist          = (int*)(ws + off);            off += (size_t)SORT_BLOCKS * BATCH * 4;
  int* offTab             = (int*)(ws + off);            off += (size_t)SORT_BLOCKS * BATCH * 4;
  float* Spart            = (float*)(ws + off);          off += (size_t)4 * 128 * 11 * 128 * 4;
  int* cntPart            = (int*)(ws + off);            off += (size_t)4 * 128 * 11 * 4;
  float* pmax4            = (float*)(ws + off);          off += (size_t)4 * 128 * 128 * 4;

  float* out0 = (float*)d_out;
  float* out1 = out0 + (size_t)N_ATOMS * 128;
  float* out2 = out1 + 16384;

  hipLaunchKernelGGL(k_build_bb, dim3((11 * 128 * 256 + 255) / 256), dim3(256), 0, stream,
                     W, b, BcatT, biascat);
  // fused cast + histogram
  hipLaunchKernelGGL(k_cast_hist, dim3(SORT_BLOCKS), dim3(512), 0, stream,
                     (const float2*)atoms, membership, (unsigned*)atomsBf, blockHist);
  hipLaunchKernelGGL(k_scan2, dim3(1), dim3(128), 0, stream, blockHist, offTab, base_, hist);
  hipLaunchKernelGGL(k_scatter2, dim3(SORT_BLOCKS), dim3(256), 0, stream, membership, offTab, perm);
  // fused nsum + activated GEMM + LN
  hipLaunchKernelGGL(k_gemm, dim3(236, 11), dim3(512), 0, stream,
                     atomsBf, adj, BcatT, biascat, gamma, beta, out0);
  // fused segment-max(xn) + per-(mol,deg) atom sums (single perm pass)
  hipLaunchKernelGGL(k_mreduce, dim3(512), dim3(512), 0, stream,
                     (const f32x2*)out0, (const unsigned*)atomsBf, perm, base_, hist,
                     Spart, cntPart, (float2*)pmax4);
  // yn (algebraic gathered path) + max merge
  hipLaunchKernelGGL(k_ynfinal, dim3(128), dim3(128), 0, stream,
                     Spart, cntPart, W, b, gamma, beta, pmax4, out1, out2);
}

// Round 13
// 561.319 us; speedup vs baseline: 1.6166x; 1.0622x over previous
//
#include <hip/hip_runtime.h>
#include <stdint.h>

#define MAX_DEG   10
#define DEG_COUNT 30000
#define N_ATOMS   330000      // 11 * 30000
#define NF        128
#define BATCH     128
#define SORT_BLOCKS 256
#define SORT_CHUNK  1290      // ceil(330000/256)
#define NB_BUILD  1408        // 11*128*256/256
#define NB_CAST   41250       // N_ATOMS*128/4/256

typedef __attribute__((ext_vector_type(8))) short bf16x8;   // 8 bf16 (4 VGPRs)
typedef __attribute__((ext_vector_type(4))) float f32x4;
typedef __attribute__((ext_vector_type(2))) float f32x2;

__device__ __forceinline__ float bf2f(unsigned short h) {
  union { unsigned u; float f; } v; v.u = ((unsigned)h) << 16; return v.f;
}
__device__ __forceinline__ unsigned short f2bf(float f) {
  union { float f; unsigned u; } v; v.f = f;
  unsigned u = v.u;
  unsigned r = (u + 0x7fffu + ((u >> 16) & 1u)) >> 16;   // RNE
  return (unsigned short)r;
}

struct AdjPtrs { const int* p[10]; };

#define NEG_INF_BITS 0xFF800000

// ---------------------------------------------------------------------------
// K_prep: block-range dispatch — three independent jobs, one launch, each at
// its natural parallelism (round-12 lesson: fusing hist INTO cast's loop
// forced a 256-block grid -> 1 block/CU -> 136us for a 254MB copy).
//   [0, NB_BUILD)            : build BcatT (bf16 activated B) + biascat
//   [NB_BUILD, +NB_CAST)     : fp32 atoms -> packed bf16 copy (full width)
//   last SORT_BLOCKS blocks  : per-chunk membership histogram (int LDS
//                              atomics, native), written TRANSPOSED.
// ---------------------------------------------------------------------------
__global__ __launch_bounds__(256) void k_prep(
    const float* __restrict__ W,
    const float* __restrict__ b,
    const f32x4* __restrict__ atoms4,
    const int* __restrict__ membership,
    unsigned short* __restrict__ BcatT,     // [11][128][256]
    float* __restrict__ biascat,            // [11][128]
    ushort4* __restrict__ dst4,             // bf16 atoms copy
    int* __restrict__ blockHistT)           // [128 m][256 b]
{
  const int bx = blockIdx.x;
  const int tid = threadIdx.x;
  __shared__ int bins[BATCH];

  if (bx < NB_BUILD) {
    int idx = bx * 256 + tid;
    if (idx < 11 * 128) {           // bias: [d][n]
      int d = idx >> 7, n = idx & 127;
      float f = (d >= 1) ? (b[(2 * (d - 1)) * 128 + n] + b[(2 * d - 1) * 128 + n])
                         : b[20 * 128 + n];
      biascat[idx] = f;
    }
    if (idx < 11 * 128 * 256) {
      int d = idx >> 15;
      int rem = idx & 32767;
      int n = rem >> 8;
      int k = rem & 255;
      float v;
      if (k < 128) {
        v = (d >= 1) ? W[(2 * (d - 1)) * 16384 + k * 128 + n] : 0.f;
      } else {
        int ks = k - 128;
        int wi = (d >= 1) ? (2 * d - 1) : 20;
        v = W[wi * 16384 + ks * 128 + n];
      }
      BcatT[idx] = f2bf(v);   // idx == d*32768 + n*256 + k
    }
  } else if (bx < NB_BUILD + NB_CAST) {
    size_t i = (size_t)(bx - NB_BUILD) * 256 + tid;   // one float4 -> ushort4
    f32x4 v = __builtin_nontemporal_load(atoms4 + i);
    ushort4 o;
    o.x = f2bf(v[0]); o.y = f2bf(v[1]); o.z = f2bf(v[2]); o.w = f2bf(v[3]);
    dst4[i] = o;
  } else {
    int bh = bx - NB_BUILD - NB_CAST;     // 0..SORT_BLOCKS-1
    if (tid < BATCH) bins[tid] = 0;
    __syncthreads();
    int lo = bh * SORT_CHUNK, hi = min(lo + SORT_CHUNK, N_ATOMS);
    for (int i = lo + tid; i < hi; i += 256)
      atomicAdd(&bins[membership[i]], 1);
    __syncthreads();
    if (tid < BATCH) blockHistT[tid * 256 + bh] = bins[tid];
  }
}

// ---------------------------------------------------------------------------
// K_scan: PARALLEL scan (round-12's 1-block k_scan2 was 2x256 dependent
// global-latency iterations — a serial whale). 128 blocks (one per molecule)
// x 256 threads: coalesced read of blockHistT[m][*], block-scan, write
// exclusive offsets + molecule total. Integer math identical to k_scan2.
// ---------------------------------------------------------------------------
__global__ __launch_bounds__(256) void k_scan(
    const int* __restrict__ blockHistT,     // [128 m][256 b]
    int* __restrict__ relOffT,              // [128 m][256 b] exclusive
    int* __restrict__ tot)                  // [128]
{
  const int m = blockIdx.x;
  const int tid = threadIdx.x;              // = b
  __shared__ int ws[4];
  int v = blockHistT[m * 256 + tid];
  int x = v;
#pragma unroll
  for (int o = 1; o < 64; o <<= 1) {
    int t = __shfl_up(x, o, 64);
    if ((tid & 63) >= o) x += t;
  }
  if ((tid & 63) == 63) ws[tid >> 6] = x;
  __syncthreads();
  int wb = 0;
  for (int w = 0; w < (tid >> 6); ++w) wb += ws[w];
  int incl = wb + x;
  relOffT[m * 256 + tid] = incl - v;
  if (tid == 255) tot[m] = incl;
}

// K_scatter: seed LDS bins with base[m] + this chunk's offsets (base prefix
// recomputed per block in LDS — 128 ints, trivial), then block-local native
// int LDS atomics + plain 4B writes.
__global__ __launch_bounds__(256) void k_scatter(
    const int* __restrict__ membership,
    const int* __restrict__ relOffT,
    const int* __restrict__ tot,
    int* __restrict__ perm)
{
  __shared__ int totS[BATCH], baseS[BATCH], bins[BATCH];
  const int tid = threadIdx.x;
  if (tid < BATCH) totS[tid] = tot[tid];
  __syncthreads();
  if (tid == 0) {
    int a = 0;
    for (int i = 0; i < BATCH; ++i) { baseS[i] = a; a += totS[i]; }
  }
  __syncthreads();
  if (tid < BATCH) bins[tid] = baseS[tid] + relOffT[tid * 256 + blockIdx.x];
  __syncthreads();
  int lo = blockIdx.x * SORT_CHUNK, hi = min(lo + SORT_CHUNK, N_ATOMS);
  for (int i = lo + tid; i < hi; i += 256) {
    int m = membership[i];
    int pos = atomicAdd(&bins[m], 1);   // native int LDS atomic
    perm[pos] = i;
  }
}

// ---------------------------------------------------------------------------
// Phase-0 helper (fused nsum): one wave computes 16 nsum rows of its block
// into LDS, 2 rows/iter. Bit-identical accumulation to the old k_nsum.
// ---------------------------------------------------------------------------
template<int D>
__device__ __forceinline__ void nsum_phase0(const unsigned* __restrict__ atomsU,
                                            const int* __restrict__ abase,
                                            unsigned* __restrict__ NS,
                                            int rowTile, int wave, int lane) {
  for (int it = 0; it < 8; ++it) {
    int iloc = wave * 16 + it * 2;               // local row 0..127
    int r0 = rowTile * 128 + iloc;
    int sw0 = lane ^ ((iloc & 7) << 2);
    int sw1 = lane ^ (((iloc + 1) & 7) << 2);
    if (r0 < DEG_COUNT - 1) {                    // normal pair (r0, r0+1)
      const int* a = abase + (size_t)r0 * D;
      int myIdx = (lane < 2 * D) ? a[lane] : 0;
      unsigned xs[2 * D];
#pragma unroll
      for (int j = 0; j < 2 * D; ++j) {
        int nbr = __shfl(myIdx, j, 64);
        xs[j] = atomsU[(size_t)nbr * 64 + lane];
      }
      float s0a = 0.f, s1a = 0.f, s0b = 0.f, s1b = 0.f;
#pragma unroll
      for (int j = 0; j < D; ++j) {
        s0a += bf2f((unsigned short)(xs[j] & 0xffff));
        s1a += bf2f((unsigned short)(xs[j] >> 16));
      }
#pragma unroll
      for (int j = D; j < 2 * D; ++j) {
        s0b += bf2f((unsigned short)(xs[j] & 0xffff));
        s1b += bf2f((unsigned short)(xs[j] >> 16));
      }
      NS[(size_t)iloc * 64 + sw0]       = (unsigned)f2bf(s0a) | ((unsigned)f2bf(s1a) << 16);
      NS[(size_t)(iloc + 1) * 64 + sw1] = (unsigned)f2bf(s0b) | ((unsigned)f2bf(s1b) << 16);
    } else {                                     // tail: both rows clamp to 29999
      const int* a = abase + (size_t)(DEG_COUNT - 1) * D;
      int myIdx = (lane < D) ? a[lane] : 0;
      unsigned xs[D];
#pragma unroll
      for (int j = 0; j < D; ++j) {
        int nbr = __shfl(myIdx, j, 64);
        xs[j] = atomsU[(size_t)nbr * 64 + lane];
      }
      float s0 = 0.f, s1 = 0.f;
#pragma unroll
      for (int j = 0; j < D; ++j) {
        s0 += bf2f((unsigned short)(xs[j] & 0xffff));
        s1 += bf2f((unsigned short)(xs[j] >> 16));
      }
      unsigned p = (unsigned)f2bf(s0) | ((unsigned)f2bf(s1) << 16);
      NS[(size_t)iloc * 64 + sw0] = p;
      NS[(size_t)(iloc + 1) * 64 + sw1] = p;
    }
  }
}

// ---------------------------------------------------------------------------
// K3: fused nsum + streaming MFMA GEMM — activated half (128 cols).
// 1D grid, d = bid % 11 (heavy d=10 blocks interleaved, no dispatch tail).
// B panel prefetched to REGISTERS before phase-0 so its L2 latency hides
// under the gather phase; written to LDS after NS is consumed.
// ---------------------------------------------------------------------------
__global__ __launch_bounds__(512, 4) void k_gemm(
    const unsigned short* __restrict__ atomsBf,
    AdjPtrs adj,
    const unsigned short* __restrict__ BcatT,    // [11][128][256] n-major
    const float* __restrict__ biascat,           // [11][128]
    const float* __restrict__ gamma,
    const float* __restrict__ beta,
    float* __restrict__ out0)                    // xn FINAL (fp32)
{
  const int bid = blockIdx.x;
  const int d = bid % 11;
  const int rowTile = bid / 11;
  const int tid = threadIdx.x;
  const int lane = tid & 63;
  const int wave = tid >> 6;          // 0..7
  const int m16 = lane & 15;
  const int g = lane >> 4;            // k-group 0..3

  __shared__ unsigned short Bs[128 * 256];   // 64 KiB; phase0 NS uses first 32KB
  unsigned* NS = (unsigned*)Bs;              // [128 rows][64 words], swizzled

  const unsigned short* Bd = BcatT + d * 32768;
  const unsigned* atomsU = (const unsigned*)atomsBf;

  // ---- prefetch B panel to registers (latency hides under phase 0) ----
  uint4 bPre[8];
#pragma unroll
  for (int it = 0; it < 8; ++it) {
    int flat = it * 512 + tid;
    int row = flat >> 5;
    int c = flat & 31;
    bPre[it] = *(const uint4*)(Bd + row * 256 + c * 8);
  }

  // ---- self A-frags (ks 4-7) from global (also overlap with phase 0) ----
  const int rowBase = rowTile * 128 + wave * 16;
  bf16x8 af[8];
  {
    int rbL = rowBase + m16; if (rbL > DEG_COUNT - 1) rbL = DEG_COUNT - 1;
    size_t gr = (size_t)d * DEG_COUNT + rbL;
#pragma unroll
    for (int ks = 4; ks < 8; ++ks)
      af[ks] = *(const bf16x8*)(atomsBf + gr * 128 + (ks - 4) * 32 + g * 8);
  }

  // ---- phase 0: fused nsum into LDS; af ks0-3 from LDS ----
  if (d > 0) {
    const int* abase = adj.p[d - 1];
    switch (d) {
      case 1:  nsum_phase0<1>(atomsU, abase, NS, rowTile, wave, lane); break;
      case 2:  nsum_phase0<2>(atomsU, abase, NS, rowTile, wave, lane); break;
      case 3:  nsum_phase0<3>(atomsU, abase, NS, rowTile, wave, lane); break;
      case 4:  nsum_phase0<4>(atomsU, abase, NS, rowTile, wave, lane); break;
      case 5:  nsum_phase0<5>(atomsU, abase, NS, rowTile, wave, lane); break;
      case 6:  nsum_phase0<6>(atomsU, abase, NS, rowTile, wave, lane); break;
      case 7:  nsum_phase0<7>(atomsU, abase, NS, rowTile, wave, lane); break;
      case 8:  nsum_phase0<8>(atomsU, abase, NS, rowTile, wave, lane); break;
      case 9:  nsum_phase0<9>(atomsU, abase, NS, rowTile, wave, lane); break;
      default: nsum_phase0<10>(atomsU, abase, NS, rowTile, wave, lane); break;
    }
    __syncthreads();
    const char* nsb = (const char*)NS;
    const int rowb = (wave * 16 + m16) * 256;         // byte base, local row
    const int sw = (m16 & 7) << 4;
#pragma unroll
    for (int ks = 0; ks < 4; ++ks)
      af[ks] = *(const bf16x8*)(nsb + ((rowb + ks * 64 + g * 16) ^ sw));
    __syncthreads();   // protect NS before B-panel overwrite
  } else {
    bf16x8 z = {0, 0, 0, 0, 0, 0, 0, 0};
#pragma unroll
    for (int ks = 0; ks < 4; ++ks) af[ks] = z;
  }

  // ---- stage B from registers: 512 threads x 8 x 16B = 64KB, swizzled ----
#pragma unroll
  for (int it = 0; it < 8; ++it) {
    int flat = it * 512 + tid;
    int row = flat >> 5;              // 0..127
    int c = flat & 31;
    int kb = (c * 16) ^ ((row & 7) << 4);
    *(uint4*)((char*)Bs + row * 512 + kb) = bPre[it];
  }

  __syncthreads();

  const int ldsMask = (m16 & 7) << 4;

  f32x4 acc[8];
#pragma unroll
  for (int ct = 0; ct < 8; ++ct) acc[ct] = (f32x4){0.f, 0.f, 0.f, 0.f};

#pragma unroll
  for (int ct = 0; ct < 8; ++ct) {
    const char* bbase = (const char*)Bs + (ct * 16 + m16) * 512;
    bf16x8 bf[8];
#pragma unroll
    for (int ks = 0; ks < 8; ++ks)
      bf[ks] = *(const bf16x8*)(bbase + ((ks * 64 + g * 16) ^ ldsMask));
#pragma unroll
    for (int ks = 0; ks < 8; ++ks)
      acc[ct] = __builtin_amdgcn_mfma_f32_16x16x32_bf16(af[ks], bf[ks], acc[ct], 0, 0, 0);
  }

  // ---- epilogue: bias, LN over 128 cols, coalesced stores ----
  float bias_[8], gam[8], bet[8];
#pragma unroll
  for (int ct = 0; ct < 8; ++ct) {
    bias_[ct] = biascat[d * 128 + ct * 16 + m16];
    gam[ct] = gamma[ct * 16 + m16];
    bet[ct] = beta[ct * 16 + m16];
  }

#pragma unroll
  for (int ct = 0; ct < 8; ++ct)
#pragma unroll
    for (int r = 0; r < 4; ++r) acc[ct][r] += bias_[ct];

  float s[4], qq[4];
#pragma unroll
  for (int r = 0; r < 4; ++r) {
    s[r] = 0.f; qq[r] = 0.f;
#pragma unroll
    for (int ct = 0; ct < 8; ++ct) {
      float v = acc[ct][r];
      s[r] += v; qq[r] += v * v;
    }
  }
#pragma unroll
  for (int off = 8; off >= 1; off >>= 1) {
#pragma unroll
    for (int r = 0; r < 4; ++r) {
      s[r]  += __shfl_xor(s[r],  off, 64);
      qq[r] += __shfl_xor(qq[r], off, 64);
    }
  }

#pragma unroll
  for (int r = 0; r < 4; ++r) {
    int rb = rowBase + g * 4 + r;
    float mean = s[r] * (1.0f / 128.0f);
    float var  = qq[r] * (1.0f / 128.0f) - mean * mean;
    float inv  = 1.0f / (sqrtf(var + 1e-5f) + 1e-5f);   // ref: sqrt(var+eps)+eps
    if (rb < DEG_COUNT) {
      size_t grow = (size_t)d * DEG_COUNT + rb;
#pragma unroll
      for (int ct = 0; ct < 8; ++ct)
        out0[grow * 128 + ct * 16 + m16] = gam[ct] * ((acc[ct][r] - mean) * inv) + bet[ct];
    }
  }
}

// ---------------------------------------------------------------------------
// K_mreduce: ONE perm pass doing BOTH segment-max(xn) AND per-(molecule,
// degree) atom sums + counts. Per-wave LDS tables with PLAIN adds (sort
// makes each (wave,slice) range exclusive). 2-row unroll for MLP.
// base[m] recomputed per block from tot[] (trivial int prefix).
// ---------------------------------------------------------------------------
__global__ __launch_bounds__(512) void k_mreduce(
    const f32x2* __restrict__ xnV,          // out0 as f32x2
    const unsigned* __restrict__ atomsU,
    const int* __restrict__ perm,
    const int* __restrict__ tot,            // [128]
    float* __restrict__ Spart,      // [4][128][11][128]
    int* __restrict__ cntPart,      // [4][128][11]
    float2* __restrict__ pmax4)     // [4][128][64] float2
{
  const int m = blockIdx.x >> 2;
  const int s = blockIdx.x & 3;
  const int wave = threadIdx.x >> 6, lane = threadIdx.x & 63;

  __shared__ float S[8][11][128];   // physical col p: p<64 -> col 2p, else 2(p-64)+1
  __shared__ int C[8][11];
  __shared__ float2 maxT[8][64];
  __shared__ int totS[BATCH];
  __shared__ int rangeS[2];
  for (int e = lane; e < 11 * 128; e += 64) S[wave][e >> 7][e & 127] = 0.f;
  if (lane < 11) C[wave][lane] = 0;
  if (threadIdx.x < BATCH) totS[threadIdx.x] = tot[threadIdx.x];
  __syncthreads();
  if (threadIdx.x == 0) {
    int a = 0;
    for (int i = 0; i < m; ++i) a += totS[i];
    rangeS[0] = a; rangeS[1] = totS[m];
  }
  __syncthreads();
  const int b0 = rangeS[0], cnt = rangeS[1];
  const int lo = b0 + (cnt * s) / 4;
  const int hi = b0 + (cnt * (s + 1)) / 4;

  const float NEG_INF = __int_as_float((int)NEG_INF_BITS);
  float mx0 = NEG_INF, mx1 = NEG_INF;

  for (int i = lo + wave * 2; i < hi; i += 16) {
    int r0 = perm[i];
    bool has1 = (i + 1 < hi);
    int r1 = has1 ? perm[i + 1] : r0;
    f32x2 x0 = __builtin_nontemporal_load(xnV + (size_t)r0 * 64 + lane);
    unsigned a0 = __builtin_nontemporal_load(atomsU + (size_t)r0 * 64 + lane);
    f32x2 x1 = __builtin_nontemporal_load(xnV + (size_t)r1 * 64 + lane);
    unsigned a1 = __builtin_nontemporal_load(atomsU + (size_t)r1 * 64 + lane);
    int d0 = r0 / DEG_COUNT;                    // wave-uniform
    mx0 = fmaxf(mx0, x0[0]);
    mx1 = fmaxf(mx1, x0[1]);
    S[wave][d0][lane]      += bf2f((unsigned short)(a0 & 0xffff));   // plain LDS add
    S[wave][d0][64 + lane] += bf2f((unsigned short)(a0 >> 16));
    if (lane == 0) C[wave][d0]++;
    if (has1) {
      int d1 = r1 / DEG_COUNT;
      mx0 = fmaxf(mx0, x1[0]);
      mx1 = fmaxf(mx1, x1[1]);
      S[wave][d1][lane]      += bf2f((unsigned short)(a1 & 0xffff));
      S[wave][d1][64 + lane] += bf2f((unsigned short)(a1 >> 16));
      if (lane == 0) C[wave][d1]++;
    }
  }
  maxT[wave][lane] = make_float2(mx0, mx1);
  __syncthreads();

  if (threadIdx.x < 64) {
    int l = threadIdx.x;
    float2 mm = maxT[0][l];
#pragma unroll
    for (int w = 1; w < 8; ++w) {
      float2 b = maxT[w][l]; mm.x = fmaxf(mm.x, b.x); mm.y = fmaxf(mm.y, b.y);
    }
    pmax4[(s * 128 + m) * 64 + l] = mm;
  }
  for (int e = threadIdx.x; e < 11 * 128; e += 512) {
    int d = e >> 7, p = e & 127;
    float t = 0.f;
#pragma unroll
    for (int w = 0; w < 8; ++w) t += S[w][d][p];
    int col = (p < 64) ? (2 * p) : (2 * (p - 64) + 1);   // de-permute
    Spart[(((size_t)s * 128 + m) * 11 + d) * 128 + col] = t;
  }
  if (threadIdx.x < 11) {
    int t = 0;
#pragma unroll
    for (int w = 0; w < 8; ++w) t += C[w][threadIdx.x];
    cntPart[((size_t)s * 128 + m) * 11 + threadIdx.x] = t;
  }
}

// ---------------------------------------------------------------------------
// K_ynfinal: yn = LN( sum_d S[m,d] @ Wg_d + cnt[m,d]*bg_d ) -> out1, and
// merge 4 max slices -> out2. 128 blocks x 128 threads.
// ---------------------------------------------------------------------------
__global__ __launch_bounds__(128) void k_ynfinal(
    const float* __restrict__ Spart,
    const int* __restrict__ cntPart,
    const float* __restrict__ W,
    const float* __restrict__ b,
    const float* __restrict__ gamma,
    const float* __restrict__ beta,
    const float* __restrict__ pmax4,        // [4][128][128]
    float* __restrict__ out1,
    float* __restrict__ out2)
{
  int m = blockIdx.x;
  int j = threadIdx.x;

  float g = __int_as_float((int)NEG_INF_BITS);
#pragma unroll
  for (int sl = 0; sl < 4; ++sl)
    g = fmaxf(g, pmax4[(sl * 128 + m) * 128 + j]);
  out2[m * 128 + j] = g;

  __shared__ float Sm[11][128];
  __shared__ float cw[11];
  for (int e = j; e < 11 * 128; e += 128) {
    int d = e >> 7, c = e & 127;
    float t = 0.f;
#pragma unroll
    for (int sl = 0; sl < 4; ++sl)
      t += Spart[(((size_t)sl * 128 + m) * 11 + d) * 128 + c];
    Sm[d][c] = t;
  }
  if (j < 11) {
    int t = 0;
#pragma unroll
    for (int sl = 0; sl < 4; ++sl) t += cntPart[((size_t)sl * 128 + m) * 11 + j];
    cw[j] = (float)t;
  }
  __syncthreads();

  float acc = 0.f;
  for (int d = 0; d < 11; ++d) {
    int wi = (d >= 1) ? (20 + d) : 31;
    const float* Wd = W + wi * 16384;
    float a0 = 0.f, a1 = 0.f, a2 = 0.f, a3 = 0.f;
    for (int k = 0; k < 128; k += 4) {
      a0 += Sm[d][k]     * Wd[k * 128 + j];
      a1 += Sm[d][k + 1] * Wd[(k + 1) * 128 + j];
      a2 += Sm[d][k + 2] * Wd[(k + 2) * 128 + j];
      a3 += Sm[d][k + 3] * Wd[(k + 3) * 128 + j];
    }
    acc += (a0 + a1) + (a2 + a3);
    acc += cw[d] * b[wi * 128 + j];
  }

  float ws_ = acc, wq = acc * acc;
#pragma unroll
  for (int off = 32; off >= 1; off >>= 1) {
    ws_ += __shfl_xor(ws_, off, 64);
    wq  += __shfl_xor(wq, off, 64);
  }
  __shared__ float red[4];
  int wave = j >> 6, lane = j & 63;
  if (lane == 0) { red[wave * 2] = ws_; red[wave * 2 + 1] = wq; }
  __syncthreads();
  float Ssum = red[0] + red[2], Q = red[1] + red[3];
  float mean = Ssum * (1.f / 128.f);
  float var = Q * (1.f / 128.f) - mean * mean;
  float inv = 1.f / (sqrtf(var + 1e-5f) + 1e-5f);
  out1[m * 128 + j] = gamma[j] * ((acc - mean) * inv) + beta[j];
}

// ---------------------------------------------------------------------------
extern "C" void kernel_launch(void* const* d_in, const int* in_sizes, int n_in,
                              void* d_out, int out_size, void* d_ws, size_t ws_size,
                              hipStream_t stream) {
  const float* atoms = (const float*)d_in[0];
  // d_in[1] = deg_slice (unused; buckets are static)
  const int* membership = (const int*)d_in[2];
  AdjPtrs adj;
  for (int i = 0; i < 10; ++i) adj.p[i] = (const int*)d_in[3 + i];
  const float* W     = (const float*)d_in[13];
  const float* b     = (const float*)d_in[14];
  const float* gamma = (const float*)d_in[15];
  const float* beta  = (const float*)d_in[16];

  char* ws = (char*)d_ws;
  size_t off = 0;
  unsigned short* atomsBf = (unsigned short*)(ws + off); off += (size_t)N_ATOMS * 128 * 2;
  unsigned short* BcatT   = (unsigned short*)(ws + off); off += (size_t)11 * 128 * 256 * 2;
  float* biascat          = (float*)(ws + off);          off += (size_t)11 * 128 * 4;
  int* perm               = (int*)(ws + off);            off += (size_t)N_ATOMS * 4;
  int* tot                = (int*)(ws + off);            off += 512;
  int* blockHistT         = (int*)(ws + off);            off += (size_t)BATCH * SORT_BLOCKS * 4;
  int* relOffT            = (int*)(ws + off);            off += (size_t)BATCH * SORT_BLOCKS * 4;
  float* Spart            = (float*)(ws + off);          off += (size_t)4 * 128 * 11 * 128 * 4;
  int* cntPart            = (int*)(ws + off);            off += (size_t)4 * 128 * 11 * 4;
  float* pmax4            = (float*)(ws + off);          off += (size_t)4 * 128 * 128 * 4;

  float* out0 = (float*)d_out;
  float* out1 = out0 + (size_t)N_ATOMS * 128;
  float* out2 = out1 + 16384;

  // 1) build B/bias + cast + histogram (block-range dispatch, one launch)
  hipLaunchKernelGGL(k_prep, dim3(NB_BUILD + NB_CAST + SORT_BLOCKS), dim3(256), 0, stream,
                     W, b, (const f32x4*)atoms, membership,
                     BcatT, biascat, (ushort4*)atomsBf, blockHistT);
  // 2) parallel scan -> relOffT + tot
  hipLaunchKernelGGL(k_scan, dim3(128), dim3(256), 0, stream, blockHistT, relOffT, tot);
  // 3) scatter -> perm
  hipLaunchKernelGGL(k_scatter, dim3(SORT_BLOCKS), dim3(256), 0, stream,
                     membership, relOffT, tot, perm);
  // 4) fused nsum + activated GEMM + LN
  hipLaunchKernelGGL(k_gemm, dim3(236 * 11), dim3(512), 0, stream,
                     atomsBf, adj, BcatT, biascat, gamma, beta, out0);
  // 5) fused segment-max(xn) + per-(mol,deg) atom sums (single perm pass)
  hipLaunchKernelGGL(k_mreduce, dim3(512), dim3(512), 0, stream,
                     (const f32x2*)out0, (const unsigned*)atomsBf, perm, tot,
                     Spart, cntPart, (float2*)pmax4);
  // 6) yn (algebraic gathered path) + max merge
  hipLaunchKernelGGL(k_ynfinal, dim3(128), dim3(128), 0, stream,
                     Spart, cntPart, W, b, gamma, beta, pmax4, out1, out2);
}

// Round 14
// 498.532 us; speedup vs baseline: 1.8202x; 1.1259x over previous
//
#include <hip/hip_runtime.h>
#include <stdint.h>

#define MAX_DEG   10
#define DEG_COUNT 30000
#define N_ATOMS   330000      // 11 * 30000
#define NF        128
#define BATCH     128
#define SORT_BLOCKS 256
#define SORT_CHUNK  1290      // ceil(330000/256)
#define NB_BUILD  1408        // 11*128*256/256
#define NB_CAST   41250       // N_ATOMS*128/4/256

typedef __attribute__((ext_vector_type(8))) short bf16x8;   // 8 bf16 (4 VGPRs)
typedef __attribute__((ext_vector_type(4))) float f32x4;
typedef __attribute__((ext_vector_type(2))) float f32x2;

__device__ __forceinline__ float bf2f(unsigned short h) {
  union { unsigned u; float f; } v; v.u = ((unsigned)h) << 16; return v.f;
}
__device__ __forceinline__ unsigned short f2bf(float f) {
  union { float f; unsigned u; } v; v.f = f;
  unsigned u = v.u;
  unsigned r = (u + 0x7fffu + ((u >> 16) & 1u)) >> 16;   // RNE
  return (unsigned short)r;
}

struct AdjPtrs { const int* p[10]; };

#define NEG_INF_BITS 0xFF800000

// ---------------------------------------------------------------------------
// K_prep: block-range dispatch — three independent jobs, one launch, each at
// its natural parallelism.
//   [0, NB_BUILD)            : build BcatT (bf16 activated B) + biascat
//   [NB_BUILD, +NB_CAST)     : fp32 atoms -> packed bf16 copy (full width)
//   last SORT_BLOCKS blocks  : per-chunk membership histogram (int LDS
//                              atomics, native), written TRANSPOSED.
// ---------------------------------------------------------------------------
__global__ __launch_bounds__(256) void k_prep(
    const float* __restrict__ W,
    const float* __restrict__ b,
    const f32x4* __restrict__ atoms4,
    const int* __restrict__ membership,
    unsigned short* __restrict__ BcatT,     // [11][128][256]
    float* __restrict__ biascat,            // [11][128]
    ushort4* __restrict__ dst4,             // bf16 atoms copy
    int* __restrict__ blockHistT)           // [128 m][256 b]
{
  const int bx = blockIdx.x;
  const int tid = threadIdx.x;
  __shared__ int bins[BATCH];

  if (bx < NB_BUILD) {
    int idx = bx * 256 + tid;
    if (idx < 11 * 128) {           // bias: [d][n]
      int d = idx >> 7, n = idx & 127;
      float f = (d >= 1) ? (b[(2 * (d - 1)) * 128 + n] + b[(2 * d - 1) * 128 + n])
                         : b[20 * 128 + n];
      biascat[idx] = f;
    }
    if (idx < 11 * 128 * 256) {
      int d = idx >> 15;
      int rem = idx & 32767;
      int n = rem >> 8;
      int k = rem & 255;
      float v;
      if (k < 128) {
        v = (d >= 1) ? W[(2 * (d - 1)) * 16384 + k * 128 + n] : 0.f;
      } else {
        int ks = k - 128;
        int wi = (d >= 1) ? (2 * d - 1) : 20;
        v = W[wi * 16384 + ks * 128 + n];
      }
      BcatT[idx] = f2bf(v);   // idx == d*32768 + n*256 + k
    }
  } else if (bx < NB_BUILD + NB_CAST) {
    size_t i = (size_t)(bx - NB_BUILD) * 256 + tid;   // one float4 -> ushort4
    f32x4 v = __builtin_nontemporal_load(atoms4 + i);
    ushort4 o;
    o.x = f2bf(v[0]); o.y = f2bf(v[1]); o.z = f2bf(v[2]); o.w = f2bf(v[3]);
    dst4[i] = o;
  } else {
    int bh = bx - NB_BUILD - NB_CAST;     // 0..SORT_BLOCKS-1
    if (tid < BATCH) bins[tid] = 0;
    __syncthreads();
    int lo = bh * SORT_CHUNK, hi = min(lo + SORT_CHUNK, N_ATOMS);
    for (int i = lo + tid; i < hi; i += 256)
      atomicAdd(&bins[membership[i]], 1);
    __syncthreads();
    if (tid < BATCH) blockHistT[tid * 256 + bh] = bins[tid];
  }
}

// ---------------------------------------------------------------------------
// K_scan: parallel scan. 128 blocks (one per molecule) x 256 threads:
// coalesced read of blockHistT[m][*], block-scan, exclusive offsets + total.
// ---------------------------------------------------------------------------
__global__ __launch_bounds__(256) void k_scan(
    const int* __restrict__ blockHistT,     // [128 m][256 b]
    int* __restrict__ relOffT,              // [128 m][256 b] exclusive
    int* __restrict__ tot)                  // [128]
{
  const int m = blockIdx.x;
  const int tid = threadIdx.x;              // = b
  __shared__ int ws[4];
  int v = blockHistT[m * 256 + tid];
  int x = v;
#pragma unroll
  for (int o = 1; o < 64; o <<= 1) {
    int t = __shfl_up(x, o, 64);
    if ((tid & 63) >= o) x += t;
  }
  if ((tid & 63) == 63) ws[tid >> 6] = x;
  __syncthreads();
  int wb = 0;
  for (int w = 0; w < (tid >> 6); ++w) wb += ws[w];
  int incl = wb + x;
  relOffT[m * 256 + tid] = incl - v;
  if (tid == 255) tot[m] = incl;
}

// K_scatter: seed LDS bins with base[m] + this chunk's offsets, then
// block-local native int LDS atomics + plain 4B writes.
__global__ __launch_bounds__(256) void k_scatter(
    const int* __restrict__ membership,
    const int* __restrict__ relOffT,
    const int* __restrict__ tot,
    int* __restrict__ perm)
{
  __shared__ int totS[BATCH], baseS[BATCH], bins[BATCH];
  const int tid = threadIdx.x;
  if (tid < BATCH) totS[tid] = tot[tid];
  __syncthreads();
  if (tid == 0) {
    int a = 0;
    for (int i = 0; i < BATCH; ++i) { baseS[i] = a; a += totS[i]; }
  }
  __syncthreads();
  if (tid < BATCH) bins[tid] = baseS[tid] + relOffT[tid * 256 + blockIdx.x];
  __syncthreads();
  int lo = blockIdx.x * SORT_CHUNK, hi = min(lo + SORT_CHUNK, N_ATOMS);
  for (int i = lo + tid; i < hi; i += 256) {
    int m = membership[i];
    int pos = atomicAdd(&bins[m], 1);   // native int LDS atomic
    perm[pos] = i;
  }
}

// ---------------------------------------------------------------------------
// Phase-0 helper (fused nsum): one wave computes 16 nsum rows of its block
// into LDS, 2 rows/iter. Bit-identical accumulation to the old k_nsum.
// ---------------------------------------------------------------------------
template<int D>
__device__ __forceinline__ void nsum_phase0(const unsigned* __restrict__ atomsU,
                                            const int* __restrict__ abase,
                                            unsigned* __restrict__ NS,
                                            int rowTile, int wave, int lane) {
  for (int it = 0; it < 8; ++it) {
    int iloc = wave * 16 + it * 2;               // local row 0..127
    int r0 = rowTile * 128 + iloc;
    int sw0 = lane ^ ((iloc & 7) << 2);
    int sw1 = lane ^ (((iloc + 1) & 7) << 2);
    if (r0 < DEG_COUNT - 1) {                    // normal pair (r0, r0+1)
      const int* a = abase + (size_t)r0 * D;
      int myIdx = (lane < 2 * D) ? a[lane] : 0;
      unsigned xs[2 * D];
#pragma unroll
      for (int j = 0; j < 2 * D; ++j) {
        int nbr = __shfl(myIdx, j, 64);
        xs[j] = atomsU[(size_t)nbr * 64 + lane];
      }
      float s0a = 0.f, s1a = 0.f, s0b = 0.f, s1b = 0.f;
#pragma unroll
      for (int j = 0; j < D; ++j) {
        s0a += bf2f((unsigned short)(xs[j] & 0xffff));
        s1a += bf2f((unsigned short)(xs[j] >> 16));
      }
#pragma unroll
      for (int j = D; j < 2 * D; ++j) {
        s0b += bf2f((unsigned short)(xs[j] & 0xffff));
        s1b += bf2f((unsigned short)(xs[j] >> 16));
      }
      NS[(size_t)iloc * 64 + sw0]       = (unsigned)f2bf(s0a) | ((unsigned)f2bf(s1a) << 16);
      NS[(size_t)(iloc + 1) * 64 + sw1] = (unsigned)f2bf(s0b) | ((unsigned)f2bf(s1b) << 16);
    } else {                                     // tail: both rows clamp to 29999
      const int* a = abase + (size_t)(DEG_COUNT - 1) * D;
      int myIdx = (lane < D) ? a[lane] : 0;
      unsigned xs[D];
#pragma unroll
      for (int j = 0; j < D; ++j) {
        int nbr = __shfl(myIdx, j, 64);
        xs[j] = atomsU[(size_t)nbr * 64 + lane];
      }
      float s0 = 0.f, s1 = 0.f;
#pragma unroll
      for (int j = 0; j < D; ++j) {
        s0 += bf2f((unsigned short)(xs[j] & 0xffff));
        s1 += bf2f((unsigned short)(xs[j] >> 16));
      }
      unsigned p = (unsigned)f2bf(s0) | ((unsigned)f2bf(s1) << 16);
      NS[(size_t)iloc * 64 + sw0] = p;
      NS[(size_t)(iloc + 1) * 64 + sw1] = p;
    }
  }
}

// ---------------------------------------------------------------------------
// K3: fused nsum + streaming MFMA GEMM — activated half (128 cols).
// ROUND-10 BODY RESTORED EXACTLY: 2D grid (236,11), B staged global->LDS
// AFTER phase-0. (Round-13's B-register prefetch held 32 VGPRs live across
// the register-hungry gather phase -> compiler spilled it to scratch:
// FETCH +130MB, WRITE +176MB, dur 122->180us. Reverted.)
// ---------------------------------------------------------------------------
__global__ __launch_bounds__(512, 4) void k_gemm(
    const unsigned short* __restrict__ atomsBf,
    AdjPtrs adj,
    const unsigned short* __restrict__ BcatT,    // [11][128][256] n-major
    const float* __restrict__ biascat,           // [11][128]
    const float* __restrict__ gamma,
    const float* __restrict__ beta,
    float* __restrict__ out0)                    // xn FINAL (fp32)
{
  const int d = blockIdx.y;
  const int rowTile = blockIdx.x;
  const int tid = threadIdx.x;
  const int lane = tid & 63;
  const int wave = tid >> 6;          // 0..7
  const int m16 = lane & 15;
  const int g = lane >> 4;            // k-group 0..3

  __shared__ unsigned short Bs[128 * 256];   // 64 KiB; phase0 NS uses first 32KB
  unsigned* NS = (unsigned*)Bs;              // [128 rows][64 words], swizzled

  const unsigned short* Bd = BcatT + d * 32768;
  const unsigned* atomsU = (const unsigned*)atomsBf;

  // ---- self A-frags (ks 4-7) from global first (overlap with phase 0) ----
  const int rowBase = rowTile * 128 + wave * 16;
  bf16x8 af[8];
  {
    int rbL = rowBase + m16; if (rbL > DEG_COUNT - 1) rbL = DEG_COUNT - 1;
    size_t gr = (size_t)d * DEG_COUNT + rbL;
#pragma unroll
    for (int ks = 4; ks < 8; ++ks)
      af[ks] = *(const bf16x8*)(atomsBf + gr * 128 + (ks - 4) * 32 + g * 8);
  }

  // ---- phase 0: fused nsum into LDS; af ks0-3 from LDS ----
  if (d > 0) {
    const int* abase = adj.p[d - 1];
    switch (d) {
      case 1:  nsum_phase0<1>(atomsU, abase, NS, rowTile, wave, lane); break;
      case 2:  nsum_phase0<2>(atomsU, abase, NS, rowTile, wave, lane); break;
      case 3:  nsum_phase0<3>(atomsU, abase, NS, rowTile, wave, lane); break;
      case 4:  nsum_phase0<4>(atomsU, abase, NS, rowTile, wave, lane); break;
      case 5:  nsum_phase0<5>(atomsU, abase, NS, rowTile, wave, lane); break;
      case 6:  nsum_phase0<6>(atomsU, abase, NS, rowTile, wave, lane); break;
      case 7:  nsum_phase0<7>(atomsU, abase, NS, rowTile, wave, lane); break;
      case 8:  nsum_phase0<8>(atomsU, abase, NS, rowTile, wave, lane); break;
      case 9:  nsum_phase0<9>(atomsU, abase, NS, rowTile, wave, lane); break;
      default: nsum_phase0<10>(atomsU, abase, NS, rowTile, wave, lane); break;
    }
    __syncthreads();
    const char* nsb = (const char*)NS;
    const int rowb = (wave * 16 + m16) * 256;         // byte base, local row
    const int sw = (m16 & 7) << 4;
#pragma unroll
    for (int ks = 0; ks < 4; ++ks)
      af[ks] = *(const bf16x8*)(nsb + ((rowb + ks * 64 + g * 16) ^ sw));
    __syncthreads();   // protect NS before B-panel overwrite
  } else {
    bf16x8 z = {0, 0, 0, 0, 0, 0, 0, 0};
#pragma unroll
    for (int ks = 0; ks < 4; ++ks) af[ks] = z;
  }

  // ---- stage B: 512 threads x 8 x 16B = 64KB, swizzled dest ----
#pragma unroll
  for (int it = 0; it < 8; ++it) {
    int flat = it * 512 + tid;        // chunk of 16B; 32 chunks per row
    int row = flat >> 5;              // 0..127
    int c = flat & 31;
    uint4 v = *(const uint4*)(Bd + row * 256 + c * 8);
    int kb = (c * 16) ^ ((row & 7) << 4);
    *(uint4*)((char*)Bs + row * 512 + kb) = v;
  }

  __syncthreads();

  const int ldsMask = (m16 & 7) << 4;

  f32x4 acc[8];
#pragma unroll
  for (int ct = 0; ct < 8; ++ct) acc[ct] = (f32x4){0.f, 0.f, 0.f, 0.f};

#pragma unroll
  for (int ct = 0; ct < 8; ++ct) {
    const char* bbase = (const char*)Bs + (ct * 16 + m16) * 512;
    bf16x8 bf[8];
#pragma unroll
    for (int ks = 0; ks < 8; ++ks)
      bf[ks] = *(const bf16x8*)(bbase + ((ks * 64 + g * 16) ^ ldsMask));
#pragma unroll
    for (int ks = 0; ks < 8; ++ks)
      acc[ct] = __builtin_amdgcn_mfma_f32_16x16x32_bf16(af[ks], bf[ks], acc[ct], 0, 0, 0);
  }

  // ---- epilogue: bias, LN over 128 cols, coalesced stores ----
  float bias_[8], gam[8], bet[8];
#pragma unroll
  for (int ct = 0; ct < 8; ++ct) {
    bias_[ct] = biascat[d * 128 + ct * 16 + m16];
    gam[ct] = gamma[ct * 16 + m16];
    bet[ct] = beta[ct * 16 + m16];
  }

#pragma unroll
  for (int ct = 0; ct < 8; ++ct)
#pragma unroll
    for (int r = 0; r < 4; ++r) acc[ct][r] += bias_[ct];

  float s[4], qq[4];
#pragma unroll
  for (int r = 0; r < 4; ++r) {
    s[r] = 0.f; qq[r] = 0.f;
#pragma unroll
    for (int ct = 0; ct < 8; ++ct) {
      float v = acc[ct][r];
      s[r] += v; qq[r] += v * v;
    }
  }
#pragma unroll
  for (int off = 8; off >= 1; off >>= 1) {
#pragma unroll
    for (int r = 0; r < 4; ++r) {
      s[r]  += __shfl_xor(s[r],  off, 64);
      qq[r] += __shfl_xor(qq[r], off, 64);
    }
  }

#pragma unroll
  for (int r = 0; r < 4; ++r) {
    int rb = rowBase + g * 4 + r;
    float mean = s[r] * (1.0f / 128.0f);
    float var  = qq[r] * (1.0f / 128.0f) - mean * mean;
    float inv  = 1.0f / (sqrtf(var + 1e-5f) + 1e-5f);   // ref: sqrt(var+eps)+eps
    if (rb < DEG_COUNT) {
      size_t grow = (size_t)d * DEG_COUNT + rb;
#pragma unroll
      for (int ct = 0; ct < 8; ++ct)
        out0[grow * 128 + ct * 16 + m16] = gam[ct] * ((acc[ct][r] - mean) * inv) + bet[ct];
    }
  }
}

// ---------------------------------------------------------------------------
// K_mreduce: ONE perm pass doing BOTH segment-max(xn) AND per-(molecule,
// degree) atom sums + counts. Per-wave LDS tables with PLAIN adds (sort
// makes each (wave,slice) range exclusive). 2-row unroll for MLP.
// ---------------------------------------------------------------------------
__global__ __launch_bounds__(512) void k_mreduce(
    const f32x2* __restrict__ xnV,          // out0 as f32x2
    const unsigned* __restrict__ atomsU,
    const int* __restrict__ perm,
    const int* __restrict__ tot,            // [128]
    float* __restrict__ Spart,      // [4][128][11][128]
    int* __restrict__ cntPart,      // [4][128][11]
    float2* __restrict__ pmax4)     // [4][128][64] float2
{
  const int m = blockIdx.x >> 2;
  const int s = blockIdx.x & 3;
  const int wave = threadIdx.x >> 6, lane = threadIdx.x & 63;

  __shared__ float S[8][11][128];   // physical col p: p<64 -> col 2p, else 2(p-64)+1
  __shared__ int C[8][11];
  __shared__ float2 maxT[8][64];
  __shared__ int totS[BATCH];
  __shared__ int rangeS[2];
  for (int e = lane; e < 11 * 128; e += 64) S[wave][e >> 7][e & 127] = 0.f;
  if (lane < 11) C[wave][lane] = 0;
  if (threadIdx.x < BATCH) totS[threadIdx.x] = tot[threadIdx.x];
  __syncthreads();
  if (threadIdx.x == 0) {
    int a = 0;
    for (int i = 0; i < m; ++i) a += totS[i];
    rangeS[0] = a; rangeS[1] = totS[m];
  }
  __syncthreads();
  const int b0 = rangeS[0], cnt = rangeS[1];
  const int lo = b0 + (cnt * s) / 4;
  const int hi = b0 + (cnt * (s + 1)) / 4;

  const float NEG_INF = __int_as_float((int)NEG_INF_BITS);
  float mx0 = NEG_INF, mx1 = NEG_INF;

  for (int i = lo + wave * 2; i < hi; i += 16) {
    int r0 = perm[i];
    bool has1 = (i + 1 < hi);
    int r1 = has1 ? perm[i + 1] : r0;
    f32x2 x0 = __builtin_nontemporal_load(xnV + (size_t)r0 * 64 + lane);
    unsigned a0 = __builtin_nontemporal_load(atomsU + (size_t)r0 * 64 + lane);
    f32x2 x1 = __builtin_nontemporal_load(xnV + (size_t)r1 * 64 + lane);
    unsigned a1 = __builtin_nontemporal_load(atomsU + (size_t)r1 * 64 + lane);
    int d0 = r0 / DEG_COUNT;                    // wave-uniform
    mx0 = fmaxf(mx0, x0[0]);
    mx1 = fmaxf(mx1, x0[1]);
    S[wave][d0][lane]      += bf2f((unsigned short)(a0 & 0xffff));   // plain LDS add
    S[wave][d0][64 + lane] += bf2f((unsigned short)(a0 >> 16));
    if (lane == 0) C[wave][d0]++;
    if (has1) {
      int d1 = r1 / DEG_COUNT;
      mx0 = fmaxf(mx0, x1[0]);
      mx1 = fmaxf(mx1, x1[1]);
      S[wave][d1][lane]      += bf2f((unsigned short)(a1 & 0xffff));
      S[wave][d1][64 + lane] += bf2f((unsigned short)(a1 >> 16));
      if (lane == 0) C[wave][d1]++;
    }
  }
  maxT[wave][lane] = make_float2(mx0, mx1);
  __syncthreads();

  if (threadIdx.x < 64) {
    int l = threadIdx.x;
    float2 mm = maxT[0][l];
#pragma unroll
    for (int w = 1; w < 8; ++w) {
      float2 b = maxT[w][l]; mm.x = fmaxf(mm.x, b.x); mm.y = fmaxf(mm.y, b.y);
    }
    pmax4[(s * 128 + m) * 64 + l] = mm;
  }
  for (int e = threadIdx.x; e < 11 * 128; e += 512) {
    int d = e >> 7, p = e & 127;
    float t = 0.f;
#pragma unroll
    for (int w = 0; w < 8; ++w) t += S[w][d][p];
    int col = (p < 64) ? (2 * p) : (2 * (p - 64) + 1);   // de-permute
    Spart[(((size_t)s * 128 + m) * 11 + d) * 128 + col] = t;
  }
  if (threadIdx.x < 11) {
    int t = 0;
#pragma unroll
    for (int w = 0; w < 8; ++w) t += C[w][threadIdx.x];
    cntPart[((size_t)s * 128 + m) * 11 + threadIdx.x] = t;
  }
}

// ---------------------------------------------------------------------------
// K_ynfinal: yn = LN( sum_d S[m,d] @ Wg_d + cnt[m,d]*bg_d ) -> out1, and
// merge 4 max slices -> out2. 128 blocks x 128 threads.
// ---------------------------------------------------------------------------
__global__ __launch_bounds__(128) void k_ynfinal(
    const float* __restrict__ Spart,
    const int* __restrict__ cntPart,
    const float* __restrict__ W,
    const float* __restrict__ b,
    const float* __restrict__ gamma,
    const float* __restrict__ beta,
    const float* __restrict__ pmax4,        // [4][128][128]
    float* __restrict__ out1,
    float* __restrict__ out2)
{
  int m = blockIdx.x;
  int j = threadIdx.x;

  float g = __int_as_float((int)NEG_INF_BITS);
#pragma unroll
  for (int sl = 0; sl < 4; ++sl)
    g = fmaxf(g, pmax4[(sl * 128 + m) * 128 + j]);
  out2[m * 128 + j] = g;

  __shared__ float Sm[11][128];
  __shared__ float cw[11];
  for (int e = j; e < 11 * 128; e += 128) {
    int d = e >> 7, c = e & 127;
    float t = 0.f;
#pragma unroll
    for (int sl = 0; sl < 4; ++sl)
      t += Spart[(((size_t)sl * 128 + m) * 11 + d) * 128 + c];
    Sm[d][c] = t;
  }
  if (j < 11) {
    int t = 0;
#pragma unroll
    for (int sl = 0; sl < 4; ++sl) t += cntPart[((size_t)sl * 128 + m) * 11 + j];
    cw[j] = (float)t;
  }
  __syncthreads();

  float acc = 0.f;
  for (int d = 0; d < 11; ++d) {
    int wi = (d >= 1) ? (20 + d) : 31;
    const float* Wd = W + wi * 16384;
    float a0 = 0.f, a1 = 0.f, a2 = 0.f, a3 = 0.f;
    for (int k = 0; k < 128; k += 4) {
      a0 += Sm[d][k]     * Wd[k * 128 + j];
      a1 += Sm[d][k + 1] * Wd[(k + 1) * 128 + j];
      a2 += Sm[d][k + 2] * Wd[(k + 2) * 128 + j];
      a3 += Sm[d][k + 3] * Wd[(k + 3) * 128 + j];
    }
    acc += (a0 + a1) + (a2 + a3);
    acc += cw[d] * b[wi * 128 + j];
  }

  float ws_ = acc, wq = acc * acc;
#pragma unroll
  for (int off = 32; off >= 1; off >>= 1) {
    ws_ += __shfl_xor(ws_, off, 64);
    wq  += __shfl_xor(wq, off, 64);
  }
  __shared__ float red[4];
  int wave = j >> 6, lane = j & 63;
  if (lane == 0) { red[wave * 2] = ws_; red[wave * 2 + 1] = wq; }
  __syncthreads();
  float Ssum = red[0] + red[2], Q = red[1] + red[3];
  float mean = Ssum * (1.f / 128.f);
  float var = Q * (1.f / 128.f) - mean * mean;
  float inv = 1.f / (sqrtf(var + 1e-5f) + 1e-5f);
  out1[m * 128 + j] = gamma[j] * ((acc - mean) * inv) + beta[j];
}

// ---------------------------------------------------------------------------
extern "C" void kernel_launch(void* const* d_in, const int* in_sizes, int n_in,
                              void* d_out, int out_size, void* d_ws, size_t ws_size,
                              hipStream_t stream) {
  const float* atoms = (const float*)d_in[0];
  // d_in[1] = deg_slice (unused; buckets are static)
  const int* membership = (const int*)d_in[2];
  AdjPtrs adj;
  for (int i = 0; i < 10; ++i) adj.p[i] = (const int*)d_in[3 + i];
  const float* W     = (const float*)d_in[13];
  const float* b     = (const float*)d_in[14];
  const float* gamma = (const float*)d_in[15];
  const float* beta  = (const float*)d_in[16];

  char* ws = (char*)d_ws;
  size_t off = 0;
  unsigned short* atomsBf = (unsigned short*)(ws + off); off += (size_t)N_ATOMS * 128 * 2;
  unsigned short* BcatT   = (unsigned short*)(ws + off); off += (size_t)11 * 128 * 256 * 2;
  float* biascat          = (float*)(ws + off);          off += (size_t)11 * 128 * 4;
  int* perm               = (int*)(ws + off);            off += (size_t)N_ATOMS * 4;
  int* tot                = (int*)(ws + off);            off += 512;
  int* blockHistT         = (int*)(ws + off);            off += (size_t)BATCH * SORT_BLOCKS * 4;
  int* relOffT            = (int*)(ws + off);            off += (size_t)BATCH * SORT_BLOCKS * 4;
  float* Spart            = (float*)(ws + off);          off += (size_t)4 * 128 * 11 * 128 * 4;
  int* cntPart            = (int*)(ws + off);            off += (size_t)4 * 128 * 11 * 4;
  float* pmax4            = (float*)(ws + off);          off += (size_t)4 * 128 * 128 * 4;

  float* out0 = (float*)d_out;
  float* out1 = out0 + (size_t)N_ATOMS * 128;
  float* out2 = out1 + 16384;

  // 1) build B/bias + cast + histogram (block-range dispatch, one launch)
  hipLaunchKernelGGL(k_prep, dim3(NB_BUILD + NB_CAST + SORT_BLOCKS), dim3(256), 0, stream,
                     W, b, (const f32x4*)atoms, membership,
                     BcatT, biascat, (ushort4*)atomsBf, blockHistT);
  // 2) parallel scan -> relOffT + tot
  hipLaunchKernelGGL(k_scan, dim3(128), dim3(256), 0, stream, blockHistT, relOffT, tot);
  // 3) scatter -> perm
  hipLaunchKernelGGL(k_scatter, dim3(SORT_BLOCKS), dim3(256), 0, stream,
                     membership, relOffT, tot, perm);
  // 4) fused nsum + activated GEMM + LN (round-10 body)
  hipLaunchKernelGGL(k_gemm, dim3(236, 11), dim3(512), 0, stream,
                     atomsBf, adj, BcatT, biascat, gamma, beta, out0);
  // 5) fused segment-max(xn) + per-(mol,deg) atom sums (single perm pass)
  hipLaunchKernelGGL(k_mreduce, dim3(512), dim3(512), 0, stream,
                     (const f32x2*)out0, (const unsigned*)atomsBf, perm, tot,
                     Spart, cntPart, (float2*)pmax4);
  // 6) yn (algebraic gathered path) + max merge
  hipLaunchKernelGGL(k_ynfinal, dim3(128), dim3(128), 0, stream,
                     Spart, cntPart, W, b, gamma, beta, pmax4, out1, out2);
}